// Round 7
// baseline (6191.762 us; speedup 1.0000x reference)
//
#include <hip/hip_runtime.h>

typedef __attribute__((ext_vector_type(8))) short short8;
typedef __attribute__((ext_vector_type(8))) unsigned short ushort8;
typedef __attribute__((ext_vector_type(4))) float f32x4;
typedef unsigned int uint;
typedef unsigned short ushort;

#define BB 8
#define CC 64
#define NPT 32768
#define RR 32
#define R3 32768
#define RP 34
#define RP2 1156
#define RP3 39304
#define BN_EPS 1e-4f

__device__ __forceinline__ ushort f2bf(float x) {
    uint u = __float_as_uint(x);
    u = (u + 0x7FFFu + ((u >> 16) & 1u)) >> 16;
    return (ushort)u;
}

// ================= round-0 verbatim kernels (known good) =================
__global__ void k_mean(const float* __restrict__ coords, float* __restrict__ mean) {
    __shared__ float sbuf[256];
    int bd = blockIdx.x;
    const float* c = coords + (size_t)bd * NPT;
    float s = 0.f;
    for (int i = threadIdx.x; i < NPT; i += 256) s += c[i];
    sbuf[threadIdx.x] = s; __syncthreads();
    for (int off = 128; off > 0; off >>= 1) {
        if (threadIdx.x < off) sbuf[threadIdx.x] += sbuf[threadIdx.x + off];
        __syncthreads();
    }
    if (threadIdx.x == 0) mean[bd] = sbuf[0] / (float)NPT;
}

__global__ void k_maxmag(const float* __restrict__ coords, const float* __restrict__ mean,
                         float* __restrict__ maxmag) {
    __shared__ float sbuf[256];
    int b = blockIdx.x;
    float m0 = mean[b*3], m1 = mean[b*3+1], m2 = mean[b*3+2];
    const float* c = coords + (size_t)b * 3 * NPT;
    float mx = 0.f;
    for (int i = threadIdx.x; i < NPT; i += 256) {
        float x = c[i] - m0, y = c[NPT + i] - m1, z = c[2*NPT + i] - m2;
        mx = fmaxf(mx, x*x + y*y + z*z);
    }
    sbuf[threadIdx.x] = mx; __syncthreads();
    for (int off = 128; off > 0; off >>= 1) {
        if (threadIdx.x < off) sbuf[threadIdx.x] = fmaxf(sbuf[threadIdx.x], sbuf[threadIdx.x + off]);
        __syncthreads();
    }
    if (threadIdx.x == 0) maxmag[b] = sqrtf(sbuf[0]);
}

__global__ void k_norm(const float* __restrict__ coords, const float* __restrict__ mean,
                       const float* __restrict__ maxmag,
                       float* __restrict__ norm, int* __restrict__ idx, float* __restrict__ cnt) {
    int b = blockIdx.y;
    int n = blockIdx.x * 256 + threadIdx.x;
    float denom = maxmag[b] * 2.0f;
    int vi[3];
    #pragma unroll
    for (int d = 0; d < 3; d++) {
        float v = (coords[((size_t)b*3 + d)*NPT + n] - mean[b*3 + d]) / denom + 0.5f;
        v *= (float)RR;
        v = fminf(fmaxf(v, 0.0f), (float)(RR - 1));
        norm[((size_t)b*3 + d)*NPT + n] = v;
        vi[d] = (int)rintf(v);
    }
    int fl = (vi[0]*RR + vi[1])*RR + vi[2];
    idx[b*NPT + n] = fl;
    atomicAdd(&cnt[b*R3 + fl], 1.0f);
}

__global__ void k_scatter(const float* __restrict__ feat, const int* __restrict__ idx,
                          float* __restrict__ grid) {
    int b = blockIdx.z, ci = blockIdx.y;
    int n = blockIdx.x * 256 + threadIdx.x;
    atomicAdd(&grid[((size_t)(b*CC + ci))*R3 + idx[b*NPT + n]],
              feat[((size_t)(b*CC + ci))*NPT + n]);
}

__global__ void k_divcnt(float* __restrict__ grid, const float* __restrict__ cnt) {
    size_t tot = (size_t)BB * CC * R3;
    for (size_t i = (size_t)blockIdx.x*256 + threadIdx.x; i < tot; i += (size_t)gridDim.x*256) {
        int b = (int)(i >> 21);
        int v = (int)(i & (R3 - 1));
        grid[i] /= fmaxf(cnt[b*R3 + v], 1.0f);
    }
}

__global__ __launch_bounds__(256) void k_conv(const float* __restrict__ in, float* __restrict__ out,
                                              const float* __restrict__ w, const float* __restrict__ bias,
                                              float* __restrict__ ssum, float* __restrict__ ssq) {
    __shared__ float tile[3 * 34 * 34];
    int d0 = blockIdx.x, cog = blockIdx.y, b = blockIdx.z;
    int tid = threadIdx.x;
    int co0 = cog * 8;
    float acc[4][8];
    #pragma unroll
    for (int q = 0; q < 4; q++)
        #pragma unroll
        for (int j = 0; j < 8; j++) acc[q][j] = bias[co0 + j];

    for (int ci = 0; ci < CC; ci++) {
        __syncthreads();
        for (int i = tid; i < 3*34*34; i += 256) {
            int dz = i / 1156, rem = i - dz*1156;
            int r = rem / 34, cc2 = rem - r*34;
            int g0 = d0 + dz - 1, g1 = r - 1, g2 = cc2 - 1;
            float v = 0.f;
            if (g0 >= 0 && g0 < RR && g1 >= 0 && g1 < RR && g2 >= 0 && g2 < RR)
                v = in[((size_t)(b*CC + ci))*R3 + (g0*RR + g1)*RR + g2];
            tile[i] = v;
        }
        __syncthreads();
        #pragma unroll
        for (int q = 0; q < 4; q++) {
            int p = tid + q*256;
            int d1 = p >> 5, d2 = p & 31;
            float r27[27];
            #pragma unroll
            for (int k0 = 0; k0 < 3; k0++)
                #pragma unroll
                for (int k1 = 0; k1 < 3; k1++)
                    #pragma unroll
                    for (int k2 = 0; k2 < 3; k2++)
                        r27[(k0*3 + k1)*3 + k2] = tile[k0*1156 + (d1 + k1)*34 + (d2 + k2)];
            #pragma unroll
            for (int j = 0; j < 8; j++) {
                const float* wb = w + ((size_t)(co0 + j)*CC + ci)*27;
                float a = acc[q][j];
                #pragma unroll
                for (int k = 0; k < 27; k++) a = fmaf(r27[k], wb[k], a);
                acc[q][j] = a;
            }
        }
    }
    #pragma unroll
    for (int j = 0; j < 8; j++) {
        size_t obase = ((size_t)(b*CC + co0 + j))*R3 + (size_t)d0 * 1024;
        #pragma unroll
        for (int q = 0; q < 4; q++) out[obase + tid + q*256] = acc[q][j];
    }
    for (int j = 0; j < 8; j++) {
        float s = 0.f, s2 = 0.f;
        #pragma unroll
        for (int q = 0; q < 4; q++) { s += acc[q][j]; s2 += acc[q][j]*acc[q][j]; }
        __syncthreads();
        tile[tid] = s; tile[256 + tid] = s2;
        __syncthreads();
        for (int off = 128; off > 0; off >>= 1) {
            if (tid < off) { tile[tid] += tile[tid + off]; tile[256 + tid] += tile[256 + tid + off]; }
            __syncthreads();
        }
        if (tid == 0) { atomicAdd(&ssum[co0 + j], tile[0]); atomicAdd(&ssq[co0 + j], tile[256]); }
    }
}

__global__ void k_finalize(const float* __restrict__ ssum, const float* __restrict__ ssq,
                           const float* __restrict__ gamma, const float* __restrict__ beta,
                           float* __restrict__ scale, float* __restrict__ shift) {
    int c = threadIdx.x;
    const float cntf = 262144.0f;
    float m = ssum[c] / cntf;
    float v = ssq[c] / cntf - m*m;
    float sc = gamma[c] * rsqrtf(fmaxf(v, 0.0f) + BN_EPS);
    scale[c] = sc;
    shift[c] = beta[c] - m*sc;
}

__global__ void k_bnleaky(float* __restrict__ x, const float* __restrict__ scale,
                          const float* __restrict__ shift) {
    size_t tot = (size_t)BB * CC * R3;
    for (size_t i = (size_t)blockIdx.x*256 + threadIdx.x; i < tot; i += (size_t)gridDim.x*256) {
        int c = (int)((i >> 15) & 63);
        float v = x[i]*scale[c] + shift[c];
        x[i] = v >= 0.f ? v : 0.1f*v;
    }
}

__global__ void k_point_stats(const float* __restrict__ feat, const float* __restrict__ wp,
                              const float* __restrict__ bp,
                              float* __restrict__ ssum, float* __restrict__ ssq) {
    __shared__ float sb1[256], sb2[256];
    int b = blockIdx.z, co = blockIdx.y;
    int n = blockIdx.x * 256 + threadIdx.x;
    float a = bp[co];
    const float* wr = wp + co*CC;
    #pragma unroll 8
    for (int ci = 0; ci < CC; ci++)
        a = fmaf(wr[ci], feat[((size_t)(b*CC + ci))*NPT + n], a);
    sb1[threadIdx.x] = a; sb2[threadIdx.x] = a*a; __syncthreads();
    for (int off = 128; off > 0; off >>= 1) {
        if (threadIdx.x < off) {
            sb1[threadIdx.x] += sb1[threadIdx.x + off];
            sb2[threadIdx.x] += sb2[threadIdx.x + off];
        }
        __syncthreads();
    }
    if (threadIdx.x == 0) { atomicAdd(&ssum[co], sb1[0]); atomicAdd(&ssq[co], sb2[0]); }
}

__global__ void k_final(const float* __restrict__ x2, const float* __restrict__ norm,
                        const float* __restrict__ feat, const float* __restrict__ wp,
                        const float* __restrict__ bp,
                        const float* __restrict__ scale, const float* __restrict__ shift,
                        const float* __restrict__ dflag,
                        float* __restrict__ out) {
    int b = blockIdx.z, co = blockIdx.y;
    int n = blockIdx.x * 256 + threadIdx.x;
    float a = bp[co];
    const float* wr = wp + co*CC;
    #pragma unroll 8
    for (int ci = 0; ci < CC; ci++)
        a = fmaf(wr[ci], feat[((size_t)(b*CC + ci))*NPT + n], a);
    a = a*scale[co] + shift[co];
    a = fmaxf(a, 0.f);
    float v0 = norm[((size_t)b*3 + 0)*NPT + n];
    float v1 = norm[((size_t)b*3 + 1)*NPT + n];
    float v2 = norm[((size_t)b*3 + 2)*NPT + n];
    int l0 = (int)floorf(v0), l1 = (int)floorf(v1), l2 = (int)floorf(v2);
    float f0 = v0 - (float)l0, f1 = v1 - (float)l1, f2 = v2 - (float)l2;
    int h0 = min(l0 + 1, RR - 1), h1 = min(l1 + 1, RR - 1), h2 = min(l2 + 1, RR - 1);
    const float* g = x2 + ((size_t)(b*CC + co))*R3;
    float acc = 0.f;
    #pragma unroll
    for (int dx = 0; dx < 2; dx++) {
        int xi = dx ? h0 : l0; float wx = dx ? f0 : 1.f - f0;
        #pragma unroll
        for (int dy = 0; dy < 2; dy++) {
            int yi = dy ? h1 : l1; float wy = dy ? f1 : 1.f - f1;
            #pragma unroll
            for (int dz = 0; dz < 2; dz++) {
                int zi = dz ? h2 : l2; float wz = dz ? f2 : 1.f - f2;
                acc += g[(xi*RR + yi)*RR + zi] * (wx*wy*wz);
            }
        }
    }
    out[((size_t)(b*CC + co))*NPT + n] = acc + a + dflag[0];
}

// ================= producers under test =================
__global__ void k_wt(const float* __restrict__ w, ushort* __restrict__ wT) {
    int s = blockIdx.x * 256 + threadIdx.x;
    if (s >= 110592) return;
    int ci = s & 31;
    int co = (s >> 5) & 63;
    int t  = (s >> 11) % 27;
    int ch = s / (27 * 2048);
    wT[s] = f2bf(w[(size_t)co*1728 + (size_t)(ch*32 + ci)*27 + t]);
}

__global__ void k_pack_b0(const float* __restrict__ src, ushort* __restrict__ gbf) {
    int s = blockIdx.x * 256 + threadIdx.x;      // 2*RP3*4 = 314432
    if (s >= 314432) return;
    int j = s & 3;
    int tmp = s >> 2;
    int v = tmp % RP3;
    int ch = tmp / RP3;
    int gz = v / RP2; int r = v - gz*RP2;
    int gy = r / RP;  int gx = r - gy*RP;
    ushort8 o;
    if (gz >= 1 && gz <= 32 && gy >= 1 && gy <= 32 && gx >= 1 && gx <= 32) {
        int uvox = ((gz-1)*RR + (gy-1))*RR + (gx-1);
        #pragma unroll
        for (int e = 0; e < 8; e++)
            o[e] = f2bf(src[((size_t)(ch*32 + j*8 + e))*R3 + uvox]);
    } else {
        #pragma unroll
        for (int e = 0; e < 8; e++) o[e] = 0;
    }
    *(ushort8*)(gbf + ((size_t)(ch*RP3) + v)*32 + j*8) = o;
}

// ================= first-principles checkers =================
// F1: weight transform content
__global__ __launch_bounds__(256) void k_check_wt(const float* __restrict__ w,
                                                  const ushort* __restrict__ wT,
                                                  float* __restrict__ bad) {
    int s = blockIdx.x * 256 + threadIdx.x;      // grid 432*256 = 110592 exactly
    int ci = s % 32;
    int co = (s / 32) % 64;
    int t  = (s / 2048) % 27;
    int ch = s / 55296;
    ushort e = f2bf(w[(size_t)co*1728 + (size_t)(ch*32 + ci)*27 + t]);
    int pred = (wT[s] != e) ? 1 : 0;
    unsigned long long m = __ballot(pred);
    if ((threadIdx.x & 63) == 0 && m) atomicAdd(bad, (float)__popcll(m));
}

// F2: packed grid content vs unpadded f32 source
__global__ __launch_bounds__(256) void k_check_pack(const float* __restrict__ gA,
                                                    const ushort* __restrict__ gbf,
                                                    float* __restrict__ bad) {
    int s = blockIdx.x * 256 + threadIdx.x;      // grid 9826*256 = 2515456 exactly
    int ci = s % 32;
    int v  = (s / 32) % RP3;
    int ch = s / (32 * RP3);
    int gz = v / RP2, rem = v % RP2, gy = rem / RP, gx = rem % RP;
    ushort e = 0;
    if (gz >= 1 && gz <= 32 && gy >= 1 && gy <= 32 && gx >= 1 && gx <= 32)
        e = f2bf(gA[(size_t)(ch*32 + ci)*R3 + (size_t)(((gz-1)*RR + (gy-1))*RR + (gx-1))]);
    int pred = (gbf[(size_t)(ch*RP3 + v)*32 + ci] != e) ? 1 : 0;
    unsigned long long m = __ballot(pred);
    if ((threadIdx.x & 63) == 0 && m) atomicAdd(bad, (float)__popcll(m));
}

// F3: scalar conv from global bf16 buffers (no LDS, no fragments) vs ground truth
__global__ __launch_bounds__(256) void k_check_conv(const ushort* __restrict__ gbf,
                                                    const ushort* __restrict__ wT,
                                                    const float* __restrict__ expected,
                                                    float* __restrict__ bad) {
    int co = blockIdx.y;
    int vox = blockIdx.x * 256 + threadIdx.x;
    int z = vox >> 10, y = (vox >> 5) & 31, x = vox & 31;
    float acc = 0.f;
    for (int ch = 0; ch < 2; ch++)
    for (int t0 = 0; t0 < 3; t0++)
    for (int t1 = 0; t1 < 3; t1++)
    for (int t2 = 0; t2 < 3; t2++) {
        int t = (t0*3 + t1)*3 + t2;
        const ushort* wr = wT + ((size_t)ch*27 + t)*2048 + co*32;
        const ushort* ir = gbf + ((size_t)ch*RP3 + (size_t)((z+t0)*RP2 + (y+t1)*RP + (x+t2)))*32;
        for (int ci = 0; ci < 32; ci++) {
            float wv = __uint_as_float((uint)wr[ci] << 16);
            float iv = __uint_as_float((uint)ir[ci] << 16);
            acc = fmaf(iv, wv, acc);
        }
    }
    int pred = (fabsf(acc - expected[(size_t)co*R3 + vox]) > 0.25f) ? 1 : 0;
    unsigned long long m = __ballot(pred);
    if ((threadIdx.x & 63) == 0 && m) atomicAdd(bad, (float)__popcll(m));
}

// F4: verbatim staging loop, then LDS content vs f2bf(gA) first-principles
__global__ __launch_bounds__(512) void k_check_stage(const float* __restrict__ gA,
                                                     const ushort* __restrict__ gbf,
                                                     float* __restrict__ bad) {
    __shared__ uint4 lds4[3888];
    const int d0 = blockIdx.x, quad = blockIdx.y;
    const int y0 = (quad >> 1) * 16, x0 = (quad & 1) * 16;
    const int tid = threadIdx.x;
    int lbad = 0;
    for (int ch = 0; ch < 2; ch++) {
        __syncthreads();
        // --- verbatim staging loop from k_conv_mfma / k_conv_valu ---
        const char* gbase = (const char*)gbf + (size_t)ch * ((size_t)RP3 * 64);
        for (int c = tid; c < 3888; c += 512) {
            int row = c >> 2, j = c & 3;
            int z = row / 324; int rem = row - z*324;
            int y = rem / 18;  int xl = rem - y*18;
            const uint4* gsrc = (const uint4*)(gbase +
                (size_t)((d0 + z)*RP2 + (y0 + y)*RP + (x0 + xl)) * 64);
            lds4[c] = gsrc[j];
        }
        __syncthreads();
        // --- verify against first principles ---
        for (int c = tid; c < 3888; c += 512) {
            int row = c >> 2, j = c & 3;
            int z = row / 324; int rem = row - z*324;
            int y = rem / 18;  int xl = rem - y*18;
            int pz = d0 + z, py = y0 + y, px = x0 + xl;
            bool inter = (pz >= 1 && pz <= 32 && py >= 1 && py <= 32 && px >= 1 && px <= 32);
            ushort exp8[8];
            #pragma unroll
            for (int e = 0; e < 8; e++) {
                exp8[e] = 0;
                if (inter) {
                    int ci = ch*32 + j*8 + e;
                    exp8[e] = f2bf(gA[(size_t)ci*R3 +
                                      (size_t)(((pz-1)*RR + (py-1))*RR + (px-1))]);
                }
            }
            uint4 got = lds4[c];
            uint g[4] = {got.x, got.y, got.z, got.w};
            #pragma unroll
            for (int e = 0; e < 4; e++) {
                if ((ushort)(g[e] & 0xFFFFu) != exp8[e*2] ||
                    (ushort)(g[e] >> 16)    != exp8[e*2+1]) lbad = 1;
            }
        }
    }
    unsigned long long m = __ballot(lbad != 0);
    if ((tid & 63) == 0 && m) atomicAdd(bad, (float)__popcll(m));
}

__global__ void k_diagflag2(const float* __restrict__ diag, float* __restrict__ flagout) {
    if (threadIdx.x != 0) return;
    float f = 0.f;
    if (diag[0] > 0.5f) f += 100.f;                                   // wt bad
    if (diag[1] > 0.5f) f += 800.f;                                   // pack bad
    if (diag[2] > 0.5f) f += (diag[2] >= 210000.f) ? 6000.f : 3000.f; // conv formula bad
    if (diag[3] > 0.5f) f += 12000.f;                                 // staging bad
    flagout[0] = f;
}

extern "C" void kernel_launch(void* const* d_in, const int* in_sizes, int n_in,
                              void* d_out, int out_size, void* d_ws, size_t ws_size,
                              hipStream_t stream) {
    const float* feat   = (const float*)d_in[0];
    const float* coords = (const float*)d_in[1];
    const float* w1  = (const float*)d_in[2];
    const float* b1  = (const float*)d_in[3];
    const float* g1  = (const float*)d_in[4];
    const float* be1 = (const float*)d_in[5];
    const float* w2  = (const float*)d_in[6];
    const float* b2  = (const float*)d_in[7];
    const float* g2  = (const float*)d_in[8];
    const float* be2 = (const float*)d_in[9];
    const float* wp  = (const float*)d_in[10];
    const float* bp  = (const float*)d_in[11];
    const float* gp  = (const float*)d_in[12];
    const float* bep = (const float*)d_in[13];
    float* out = (float*)d_out;
    float* ws  = (float*)d_ws;

    // workspace layout (float offsets) -- identical footprint to round-0 (proven fits)
    float* mean   = ws;                        // 24
    float* maxmag = ws + 24;                   // 8
    float* stats  = ws + 32;                   // 6*64 -> [32, 416)
    float* sc     = ws + 416;                  // 6*64 -> [416, 800)
    float* diag   = ws + 800;                  // 8    -> [800, 808)
    float* norm   = ws + 1024;                 // 786432
    int*   idx    = (int*)(ws + 787456);       // 262144
    float* cnt    = ws + 1049600;              // 262144
    float* gA     = ws + 1311744;              // 16777216 -> ends 18088960
    float* gB     = ws + 18088960;             // 16777216 -> ends 34866176

    // overlays inside gA[b=1] (dead between conv1-read and conv2-write)
    ushort* wT1  = (ushort*)(ws + 3408896);    // 110592 ushort = 55296 floats -> ends 3464192
    ushort* gbf1 = (ushort*)(ws + 3464192);    // 2515456 ushort = 1257728 floats -> ends 4721920

    hipMemsetAsync(stats, 0, 384 * sizeof(float), stream);
    hipMemsetAsync(diag,  0, 8 * sizeof(float), stream);
    hipMemsetAsync(cnt,   0, 262144 * sizeof(float), stream);
    hipMemsetAsync(gA,    0, 16777216ull * sizeof(float), stream);

    k_mean  <<<24, 256, 0, stream>>>(coords, mean);
    k_maxmag<<<8, 256, 0, stream>>>(coords, mean, maxmag);
    k_norm  <<<dim3(128, 8), 256, 0, stream>>>(coords, mean, maxmag, norm, idx, cnt);
    k_scatter<<<dim3(128, 64, 8), 256, 0, stream>>>(feat, idx, gA);
    k_divcnt<<<4096, 256, 0, stream>>>(gA, cnt);

    // ---- conv1 (round-0 ground truth) ----
    k_conv<<<dim3(32, 8, 8), 256, 0, stream>>>(gA, gB, w1, b1, stats, stats + 64);

    // ---- diagnostic battery on conv1 path (b=0) ----
    k_wt<<<432, 256, 0, stream>>>(w1, wT1);
    k_pack_b0<<<1229, 256, 0, stream>>>(gA, gbf1);
    k_check_wt<<<432, 256, 0, stream>>>(w1, wT1, diag + 0);
    k_check_pack<<<9826, 256, 0, stream>>>(gA, gbf1, diag + 1);
    k_check_conv<<<dim3(128, 64), 256, 0, stream>>>(gbf1, wT1, gB, diag + 2);
    k_check_stage<<<dim3(32, 4), 512, 0, stream>>>(gA, gbf1, diag + 3);

    k_finalize<<<1, 64, 0, stream>>>(stats, stats + 64, g1, be1, sc, sc + 64);
    k_bnleaky<<<4096, 256, 0, stream>>>(gB, sc, sc + 64);

    // ---- conv2 (round-0) ----
    k_conv<<<dim3(32, 8, 8), 256, 0, stream>>>(gB, gA, w2, b2, stats + 128, stats + 192);
    k_finalize<<<1, 64, 0, stream>>>(stats + 128, stats + 192, g2, be2, sc + 128, sc + 192);
    k_bnleaky<<<4096, 256, 0, stream>>>(gA, sc + 128, sc + 192);

    // ---- point branch + final (round-0) ----
    k_point_stats<<<dim3(128, 64, 8), 256, 0, stream>>>(feat, wp, bp, stats + 256, stats + 320);
    k_finalize<<<1, 64, 0, stream>>>(stats + 256, stats + 320, gp, bep, sc + 256, sc + 320);

    k_diagflag2<<<1, 1, 0, stream>>>(diag, diag + 6);
    k_final<<<dim3(128, 64, 8), 256, 0, stream>>>(gA, norm, feat, wp, bp, sc + 256, sc + 320,
                                                  diag + 6, out);
}

// Round 8
// 1975.079 us; speedup vs baseline: 3.1349x; 3.1349x over previous
//
#include <hip/hip_runtime.h>

typedef __attribute__((ext_vector_type(8))) short short8;
typedef __attribute__((ext_vector_type(8))) unsigned short ushort8;
typedef __attribute__((ext_vector_type(4))) float f32x4;
typedef unsigned int uint;
typedef unsigned short ushort;

#define BB 8
#define CC 64
#define NPT 32768
#define RR 32
#define R3 32768
#define RP 34
#define RP2 1156
#define RP3 39304
#define BN_EPS 1e-4f

__device__ __forceinline__ ushort f2bf(float x) {
    uint u = __float_as_uint(x);
    u = (u + 0x7FFFu + ((u >> 16) & 1u)) >> 16;
    return (ushort)u;
}

// ---------------- coord normalization ----------------
__global__ void k_mean(const float* __restrict__ coords, float* __restrict__ mean) {
    __shared__ float sbuf[256];
    int bd = blockIdx.x;
    const float* c = coords + (size_t)bd * NPT;
    float s = 0.f;
    for (int i = threadIdx.x; i < NPT; i += 256) s += c[i];
    sbuf[threadIdx.x] = s; __syncthreads();
    for (int off = 128; off > 0; off >>= 1) {
        if (threadIdx.x < off) sbuf[threadIdx.x] += sbuf[threadIdx.x + off];
        __syncthreads();
    }
    if (threadIdx.x == 0) mean[bd] = sbuf[0] / (float)NPT;
}

__global__ void k_maxmag(const float* __restrict__ coords, const float* __restrict__ mean,
                         float* __restrict__ maxmag) {
    __shared__ float sbuf[256];
    int b = blockIdx.x;
    float m0 = mean[b*3], m1 = mean[b*3+1], m2 = mean[b*3+2];
    const float* c = coords + (size_t)b * 3 * NPT;
    float mx = 0.f;
    for (int i = threadIdx.x; i < NPT; i += 256) {
        float x = c[i] - m0, y = c[NPT + i] - m1, z = c[2*NPT + i] - m2;
        mx = fmaxf(mx, x*x + y*y + z*z);
    }
    sbuf[threadIdx.x] = mx; __syncthreads();
    for (int off = 128; off > 0; off >>= 1) {
        if (threadIdx.x < off) sbuf[threadIdx.x] = fmaxf(sbuf[threadIdx.x], sbuf[threadIdx.x + off]);
        __syncthreads();
    }
    if (threadIdx.x == 0) maxmag[b] = sqrtf(sbuf[0]);
}

__global__ void k_norm(const float* __restrict__ coords, const float* __restrict__ mean,
                       const float* __restrict__ maxmag,
                       float* __restrict__ norm, int* __restrict__ idx, float* __restrict__ cnt) {
    int b = blockIdx.y;
    int n = blockIdx.x * 256 + threadIdx.x;
    float denom = maxmag[b] * 2.0f;
    int vi[3];
    #pragma unroll
    for (int d = 0; d < 3; d++) {
        float v = (coords[((size_t)b*3 + d)*NPT + n] - mean[b*3 + d]) / denom + 0.5f;
        v *= (float)RR;
        v = fminf(fmaxf(v, 0.0f), (float)(RR - 1));
        norm[((size_t)b*3 + d)*NPT + n] = v;
        vi[d] = (int)rintf(v);
    }
    int fl = (vi[0]*RR + vi[1])*RR + vi[2];
    idx[b*NPT + n] = fl;
    atomicAdd(&cnt[b*R3 + fl], 1.0f);
}

// ---------------- voxelize (round-0 verbatim) ----------------
__global__ void k_scatter(const float* __restrict__ feat, const int* __restrict__ idx,
                          float* __restrict__ grid) {
    int b = blockIdx.z, ci = blockIdx.y;
    int n = blockIdx.x * 256 + threadIdx.x;
    atomicAdd(&grid[((size_t)(b*CC + ci))*R3 + idx[b*NPT + n]],
              feat[((size_t)(b*CC + ci))*NPT + n]);
}

__global__ void k_divcnt(float* __restrict__ grid, const float* __restrict__ cnt) {
    size_t tot = (size_t)BB * CC * R3;
    for (size_t i = (size_t)blockIdx.x*256 + threadIdx.x; i < tot; i += (size_t)gridDim.x*256) {
        int b = (int)(i >> 21);
        int v = (int)(i & (R3 - 1));
        grid[i] /= fmaxf(cnt[b*R3 + v], 1.0f);
    }
}

// ---------------- bf16 transforms (verified round-7) ----------------
// weight transpose: [co][ci][27] f32 -> [2ch][27][64co][32ci] bf16
__global__ void k_wt(const float* __restrict__ w, ushort* __restrict__ wT) {
    int s = blockIdx.x * 256 + threadIdx.x;     // grid 432*256 = 110592 exactly
    int ci = s & 31;
    int co = (s >> 5) & 63;
    int t  = (s >> 11) % 27;
    int ch = s / 55296;
    wT[s] = f2bf(w[(size_t)co*1728 + (size_t)(ch*32 + ci)*27 + t]);
}

// pack: channel-first f32 [b][64][R3] -> padded channel-last bf16 [b][2][RP3][32]
__global__ void k_pack(const float* __restrict__ src, ushort* __restrict__ gbf) {
    int s = blockIdx.x * 256 + threadIdx.x;      // grid 9826*256 = 2515456 exactly
    int j = s & 3;
    int tmp = s >> 2;
    int v = tmp % RP3;
    int t2 = tmp / RP3;
    int ch = t2 & 1, b = t2 >> 1;
    int gz = v / RP2; int r = v - gz*RP2;
    int gy = r / RP;  int gx = r - gy*RP;
    ushort8 o;
    if (gz >= 1 && gz <= 32 && gy >= 1 && gy <= 32 && gx >= 1 && gx <= 32) {
        int uvox = ((gz-1)*RR + (gy-1))*RR + (gx-1);
        #pragma unroll
        for (int e = 0; e < 8; e++)
            o[e] = f2bf(src[((size_t)(b*CC + ch*32 + j*8 + e))*R3 + uvox]);
    } else {
        #pragma unroll
        for (int e = 0; e < 8; e++) o[e] = 0;
    }
    *(ushort8*)(gbf + ((size_t)((b*2 + ch)*RP3) + v)*32 + j*8) = o;
}

// ---------------- MFMA conv (components verified round-4/6/7) ----------------
__global__ __launch_bounds__(512) void k_conv_mfma(
    const ushort* __restrict__ gbf,   // [8][2][RP3][32] bf16
    const ushort* __restrict__ wT,    // [2][27][64][32] bf16
    float* __restrict__ outr)         // [8][64][R3] channel-first f32
{
    __shared__ uint4 lds4[3888];      // [3][18][18] rows x 4 chunks, 62208 B
    const int d0 = blockIdx.x, quad = blockIdx.y, b = blockIdx.z;
    const int y0 = (quad >> 1) * 16, x0 = (quad & 1) * 16;
    const int tid = threadIdx.x;
    const int lane = tid & 63;
    const int wid = tid >> 6;
    const int mgroup = wid & 1, ngroup = wid >> 1;
    const int l15 = lane & 15, kgrp = lane >> 4;

    f32x4 acc[2][4];
    #pragma unroll
    for (int mf = 0; mf < 2; mf++)
        #pragma unroll
        for (int f = 0; f < 4; f++) acc[mf][f] = (f32x4)(0.0f);

    for (int ch = 0; ch < 2; ch++) {
        __syncthreads();
        const char* gbase = (const char*)gbf + (size_t)(b*2 + ch) * ((size_t)RP3 * 64);
        for (int c = tid; c < 3888; c += 512) {
            int row = c >> 2, j = c & 3;
            int z = row / 324; int rem = row - z*324;
            int y = rem / 18;  int xl = rem - y*18;
            const uint4* gsrc = (const uint4*)(gbase +
                (size_t)((d0 + z)*RP2 + (y0 + y)*RP + (x0 + xl)) * 64);
            lds4[c] = gsrc[j];
        }
        __syncthreads();

        const ushort* wbase = wT + (size_t)ch * 27 * 2048;
        #pragma unroll
        for (int t0 = 0; t0 < 3; t0++)
        #pragma unroll
        for (int t1 = 0; t1 < 3; t1++)
        #pragma unroll
        for (int t2 = 0; t2 < 3; t2++) {
            int t = (t0*3 + t1)*3 + t2;
            short8 afr[2];
            #pragma unroll
            for (int mf = 0; mf < 2; mf++) {
                int co = mgroup*32 + mf*16 + l15;
                afr[mf] = *(const short8*)(wbase + (size_t)t*2048 + co*32 + kgrp*8);
            }
            int x = l15 + t2;
            #pragma unroll
            for (int f = 0; f < 4; f++) {
                int y = ngroup*4 + f + t1;
                int vox = (t0*18 + y)*18 + x;
                short8 bfr = *(const short8*)((const char*)lds4 + vox*64 + kgrp*16);
                acc[0][f] = __builtin_amdgcn_mfma_f32_16x16x32_bf16(afr[0], bfr, acc[0][f], 0, 0, 0);
                acc[1][f] = __builtin_amdgcn_mfma_f32_16x16x32_bf16(afr[1], bfr, acc[1][f], 0, 0, 0);
            }
        }
    }
    // C/D: col = lane&15 (spatial x), row = kgrp*4 + e (co within 16-block)
    int d2 = x0 + l15;
    #pragma unroll
    for (int f = 0; f < 4; f++) {
        int d1 = y0 + ngroup*4 + f;
        int vox = (d0*RR + d1)*RR + d2;
        #pragma unroll
        for (int mf = 0; mf < 2; mf++) {
            #pragma unroll
            for (int e = 0; e < 4; e++) {
                int co = mgroup*32 + mf*16 + kgrp*4 + e;
                outr[((size_t)(b*CC + co))*R3 + vox] = acc[mf][f][e];
            }
        }
    }
}

// ---------------- BN pieces ----------------
__global__ __launch_bounds__(256) void k_stats_cf(const float* __restrict__ x,
                                                  float* __restrict__ gs, float* __restrict__ gq) {
    __shared__ float ss[256], sq[256];
    int co = blockIdx.x, b = blockIdx.y;
    const float* p = x + ((size_t)(b*CC + co))*R3;
    float s = 0.f, q = 0.f;
    for (int i = threadIdx.x; i < R3; i += 256) { float v = p[i]; s += v; q += v*v; }
    int tid = threadIdx.x;
    ss[tid] = s; sq[tid] = q; __syncthreads();
    for (int off = 128; off > 0; off >>= 1) {
        if (tid < off) { ss[tid] += ss[tid + off]; sq[tid] += sq[tid + off]; }
        __syncthreads();
    }
    if (tid == 0) { atomicAdd(&gs[co], ss[0]); atomicAdd(&gq[co], sq[0]); }
}

__global__ void k_finalize(const float* __restrict__ ssum, const float* __restrict__ ssq,
                           const float* __restrict__ gamma, const float* __restrict__ beta,
                           float* __restrict__ scale, float* __restrict__ shift) {
    int c = threadIdx.x;
    const float cntf = 262144.0f;
    float m = ssum[c] / cntf;
    float v = ssq[c] / cntf - m*m;
    float sc = gamma[c] * rsqrtf(fmaxf(v, 0.0f) + BN_EPS);
    scale[c] = sc;
    shift[c] = beta[c] - m*sc;
}

__global__ void k_bnleaky(float* __restrict__ x, const float* __restrict__ scale,
                          const float* __restrict__ shift) {
    size_t tot = (size_t)BB * CC * R3;
    for (size_t i = (size_t)blockIdx.x*256 + threadIdx.x; i < tot; i += (size_t)gridDim.x*256) {
        int c = (int)((i >> 15) & 63);
        float v = x[i]*scale[c] + shift[c];
        x[i] = v >= 0.f ? v : 0.1f*v;
    }
}

// ---------------- point branch (round-0 verbatim) ----------------
__global__ void k_point_stats(const float* __restrict__ feat, const float* __restrict__ wp,
                              const float* __restrict__ bp,
                              float* __restrict__ ssum, float* __restrict__ ssq) {
    __shared__ float sb1[256], sb2[256];
    int b = blockIdx.z, co = blockIdx.y;
    int n = blockIdx.x * 256 + threadIdx.x;
    float a = bp[co];
    const float* wr = wp + co*CC;
    #pragma unroll 8
    for (int ci = 0; ci < CC; ci++)
        a = fmaf(wr[ci], feat[((size_t)(b*CC + ci))*NPT + n], a);
    sb1[threadIdx.x] = a; sb2[threadIdx.x] = a*a; __syncthreads();
    for (int off = 128; off > 0; off >>= 1) {
        if (threadIdx.x < off) {
            sb1[threadIdx.x] += sb1[threadIdx.x + off];
            sb2[threadIdx.x] += sb2[threadIdx.x + off];
        }
        __syncthreads();
    }
    if (threadIdx.x == 0) { atomicAdd(&ssum[co], sb1[0]); atomicAdd(&ssq[co], sb2[0]); }
}

__global__ void k_final(const float* __restrict__ x2, const float* __restrict__ norm,
                        const float* __restrict__ feat, const float* __restrict__ wp,
                        const float* __restrict__ bp,
                        const float* __restrict__ scale, const float* __restrict__ shift,
                        float* __restrict__ out) {
    int b = blockIdx.z, co = blockIdx.y;
    int n = blockIdx.x * 256 + threadIdx.x;
    float a = bp[co];
    const float* wr = wp + co*CC;
    #pragma unroll 8
    for (int ci = 0; ci < CC; ci++)
        a = fmaf(wr[ci], feat[((size_t)(b*CC + ci))*NPT + n], a);
    a = a*scale[co] + shift[co];
    a = fmaxf(a, 0.f);
    float v0 = norm[((size_t)b*3 + 0)*NPT + n];
    float v1 = norm[((size_t)b*3 + 1)*NPT + n];
    float v2 = norm[((size_t)b*3 + 2)*NPT + n];
    int l0 = (int)floorf(v0), l1 = (int)floorf(v1), l2 = (int)floorf(v2);
    float f0 = v0 - (float)l0, f1 = v1 - (float)l1, f2 = v2 - (float)l2;
    int h0 = min(l0 + 1, RR - 1), h1 = min(l1 + 1, RR - 1), h2 = min(l2 + 1, RR - 1);
    const float* g = x2 + ((size_t)(b*CC + co))*R3;
    float acc = 0.f;
    #pragma unroll
    for (int dx = 0; dx < 2; dx++) {
        int xi = dx ? h0 : l0; float wx = dx ? f0 : 1.f - f0;
        #pragma unroll
        for (int dy = 0; dy < 2; dy++) {
            int yi = dy ? h1 : l1; float wy = dy ? f1 : 1.f - f1;
            #pragma unroll
            for (int dz = 0; dz < 2; dz++) {
                int zi = dz ? h2 : l2; float wz = dz ? f2 : 1.f - f2;
                acc += g[(xi*RR + yi)*RR + zi] * (wx*wy*wz);
            }
        }
    }
    out[((size_t)(b*CC + co))*NPT + n] = acc + a;
}

extern "C" void kernel_launch(void* const* d_in, const int* in_sizes, int n_in,
                              void* d_out, int out_size, void* d_ws, size_t ws_size,
                              hipStream_t stream) {
    const float* feat   = (const float*)d_in[0];
    const float* coords = (const float*)d_in[1];
    const float* w1  = (const float*)d_in[2];
    const float* g1  = (const float*)d_in[4];
    const float* be1 = (const float*)d_in[5];
    const float* w2  = (const float*)d_in[6];
    const float* g2  = (const float*)d_in[8];
    const float* be2 = (const float*)d_in[9];
    const float* wp  = (const float*)d_in[10];
    const float* bp  = (const float*)d_in[11];
    const float* gp  = (const float*)d_in[12];
    const float* bep = (const float*)d_in[13];
    float* out = (float*)d_out;
    float* ws  = (float*)d_ws;

    // workspace layout (float offsets) -- carefully audited:
    //   wT1: 110592 ushort = 55296 floats
    //   wT2: 110592 ushort = 55296 floats
    //   gbf: 20123648 ushort = 10061824 floats
    float* mean   = ws;                        // [0, 24)
    float* maxmag = ws + 24;                   // [24, 32)
    float* stats  = ws + 32;                   // [32, 416)   s1,q1,s2,q2,sp,qp
    float* sc     = ws + 416;                  // [416, 800)  sc1,sh1,sc2,sh2,scp,shp
    float* norm   = ws + 1024;                 // [1024, 787456)
    int*   idx    = (int*)(ws + 787456);       // [787456, 1049600)
    float* cnt    = ws + 1049600;              // [1049600, 1311744)
    float* gA     = ws + 1311744;              // [1311744, 18088960)
    ushort* wT1   = (ushort*)(ws + 18088960);  // [18088960, 18144256)
    ushort* wT2   = (ushort*)(ws + 18144256);  // [18144256, 18199552)
    ushort* gbf   = (ushort*)(ws + 18199552);  // [18199552, 28261376)  -> 113.0 MB total

    hipMemsetAsync(stats, 0, 384 * sizeof(float), stream);
    hipMemsetAsync(cnt,   0, 262144 * sizeof(float), stream);
    hipMemsetAsync(gA,    0, 16777216ull * sizeof(float), stream);

    k_wt<<<432, 256, 0, stream>>>(w1, wT1);
    k_wt<<<432, 256, 0, stream>>>(w2, wT2);

    k_mean  <<<24, 256, 0, stream>>>(coords, mean);
    k_maxmag<<<8, 256, 0, stream>>>(coords, mean, maxmag);
    k_norm  <<<dim3(128, 8), 256, 0, stream>>>(coords, mean, maxmag, norm, idx, cnt);
    k_scatter<<<dim3(128, 64, 8), 256, 0, stream>>>(feat, idx, gA);
    k_divcnt<<<4096, 256, 0, stream>>>(gA, cnt);

    // conv1: gA -> gbf (bf16) -> gA (raw f32); bias omitted (cancels in BN)
    k_pack<<<9826, 256, 0, stream>>>(gA, gbf);
    k_conv_mfma<<<dim3(32, 4, 8), 512, 0, stream>>>(gbf, wT1, gA);
    k_stats_cf<<<dim3(64, 8), 256, 0, stream>>>(gA, stats + 0, stats + 64);
    k_finalize<<<1, 64, 0, stream>>>(stats + 0, stats + 64, g1, be1, sc + 0, sc + 64);
    k_bnleaky<<<4096, 256, 0, stream>>>(gA, sc + 0, sc + 64);

    // conv2: gA -> gbf (bf16) -> gA (raw f32)
    k_pack<<<9826, 256, 0, stream>>>(gA, gbf);
    k_conv_mfma<<<dim3(32, 4, 8), 512, 0, stream>>>(gbf, wT2, gA);
    k_stats_cf<<<dim3(64, 8), 256, 0, stream>>>(gA, stats + 128, stats + 192);
    k_finalize<<<1, 64, 0, stream>>>(stats + 128, stats + 192, g2, be2, sc + 128, sc + 192);
    k_bnleaky<<<4096, 256, 0, stream>>>(gA, sc + 128, sc + 192);

    // point branch + final (round-0 verbatim)
    k_point_stats<<<dim3(128, 64, 8), 256, 0, stream>>>(feat, wp, bp, stats + 256, stats + 320);
    k_finalize<<<1, 64, 0, stream>>>(stats + 256, stats + 320, gp, bep, sc + 256, sc + 320);
    k_final<<<dim3(128, 64, 8), 256, 0, stream>>>(gA, norm, feat, wp, bp, sc + 256, sc + 320, out);
}

// Round 9
// 1345.199 us; speedup vs baseline: 4.6029x; 1.4682x over previous
//
#include <hip/hip_runtime.h>

typedef __attribute__((ext_vector_type(8))) short short8;
typedef __attribute__((ext_vector_type(8))) unsigned short ushort8;
typedef __attribute__((ext_vector_type(4))) float f32x4;
typedef unsigned int uint;
typedef unsigned short ushort;

#define BB 8
#define CC 64
#define NPT 32768
#define RR 32
#define R3 32768
#define RP 34
#define RP2 1156
#define RP3 39304
#define BN_EPS 1e-4f

__device__ __forceinline__ ushort f2bf(float x) {
    uint u = __float_as_uint(x);
    u = (u + 0x7FFFu + ((u >> 16) & 1u)) >> 16;
    return (ushort)u;
}

// ---------------- coord normalization ----------------
__global__ void k_mean(const float* __restrict__ coords, float* __restrict__ mean) {
    __shared__ float sbuf[256];
    int bd = blockIdx.x;
    const float* c = coords + (size_t)bd * NPT;
    float s = 0.f;
    for (int i = threadIdx.x; i < NPT; i += 256) s += c[i];
    sbuf[threadIdx.x] = s; __syncthreads();
    for (int off = 128; off > 0; off >>= 1) {
        if (threadIdx.x < off) sbuf[threadIdx.x] += sbuf[threadIdx.x + off];
        __syncthreads();
    }
    if (threadIdx.x == 0) mean[bd] = sbuf[0] / (float)NPT;
}

__global__ void k_maxmag(const float* __restrict__ coords, const float* __restrict__ mean,
                         float* __restrict__ maxmag) {
    __shared__ float sbuf[256];
    int b = blockIdx.x;
    float m0 = mean[b*3], m1 = mean[b*3+1], m2 = mean[b*3+2];
    const float* c = coords + (size_t)b * 3 * NPT;
    float mx = 0.f;
    for (int i = threadIdx.x; i < NPT; i += 256) {
        float x = c[i] - m0, y = c[NPT + i] - m1, z = c[2*NPT + i] - m2;
        mx = fmaxf(mx, x*x + y*y + z*z);
    }
    sbuf[threadIdx.x] = mx; __syncthreads();
    for (int off = 128; off > 0; off >>= 1) {
        if (threadIdx.x < off) sbuf[threadIdx.x] = fmaxf(sbuf[threadIdx.x], sbuf[threadIdx.x + off]);
        __syncthreads();
    }
    if (threadIdx.x == 0) maxmag[b] = sqrtf(sbuf[0]);
}

// writes PADDED flat voxel index pf (components in [1,32])
__global__ void k_norm(const float* __restrict__ coords, const float* __restrict__ mean,
                       const float* __restrict__ maxmag,
                       float* __restrict__ norm, int* __restrict__ pidx, float* __restrict__ cnt) {
    int b = blockIdx.y;
    int n = blockIdx.x * 256 + threadIdx.x;
    float denom = maxmag[b] * 2.0f;
    int vi[3];
    #pragma unroll
    for (int d = 0; d < 3; d++) {
        float v = (coords[((size_t)b*3 + d)*NPT + n] - mean[b*3 + d]) / denom + 0.5f;
        v *= (float)RR;
        v = fminf(fmaxf(v, 0.0f), (float)(RR - 1));
        norm[((size_t)b*3 + d)*NPT + n] = v;
        vi[d] = (int)rintf(v);
    }
    int pf = ((vi[0]+1)*RP + (vi[1]+1))*RP + (vi[2]+1);
    pidx[b*NPT + n] = pf;
    atomicAdd(&cnt[b*RP3 + pf], 1.0f);
}

// ---------------- feat transpose: [b][64][N] -> [b][N][64] ----------------
__global__ __launch_bounds__(256) void k_transpose(const float* __restrict__ feat,
                                                   float* __restrict__ featT) {
    __shared__ float t[64][65];
    int b = blockIdx.y;
    int n0 = blockIdx.x * 64;
    for (int i = threadIdx.x; i < 4096; i += 256) {
        int ci = i >> 6, nl = i & 63;
        t[ci][nl] = feat[((size_t)(b*CC + ci))*NPT + n0 + nl];
    }
    __syncthreads();
    for (int i = threadIdx.x; i < 4096; i += 256) {
        int nl = i >> 6, ci = i & 63;
        featT[((size_t)b*NPT + n0 + nl)*64 + ci] = t[ci][nl];
    }
}

// ---------------- channel-last scatter into padded f32 grid ----------------
__global__ void k_scatter_cl(const float* __restrict__ featT, const int* __restrict__ pidx,
                             float* __restrict__ gridf) {
    int b = blockIdx.y;
    int pt = blockIdx.x * 4 + (threadIdx.x >> 6);
    int ci = threadIdx.x & 63;
    atomicAdd(&gridf[((size_t)b*RP3 + pidx[b*NPT + pt])*64 + ci],
              featT[((size_t)b*NPT + pt)*64 + ci]);
}

// ---------------- fused divide-by-count + pack to bf16 [b][2][RP3][32] --------
__global__ void k_divpack(const float* __restrict__ gridf, const float* __restrict__ cnt,
                          ushort* __restrict__ gbf) {
    int s = blockIdx.x * 256 + threadIdx.x;      // grid 9826*256 = 2515456 exactly
    int j = s & 3;
    int tmp = s >> 2;
    int v = tmp % RP3;
    int t2 = tmp / RP3;
    int ch = t2 & 1, b = t2 >> 1;
    float rc = 1.0f / fmaxf(cnt[b*RP3 + v], 1.0f);
    const f32x4* src = (const f32x4*)(gridf + ((size_t)b*RP3 + v)*64 + ch*32 + j*8);
    f32x4 a = src[0], c4 = src[1];
    ushort8 o;
    #pragma unroll
    for (int e = 0; e < 4; e++) { o[e] = f2bf(a[e]*rc); o[4+e] = f2bf(c4[e]*rc); }
    *(ushort8*)(gbf + ((size_t)((b*2 + ch)*RP3) + v)*32 + j*8) = o;
}

// ---------------- bf16 transforms (verified round-7) ----------------
__global__ void k_wt(const float* __restrict__ w, ushort* __restrict__ wT) {
    int s = blockIdx.x * 256 + threadIdx.x;     // grid 432*256 = 110592 exactly
    int ci = s & 31;
    int co = (s >> 5) & 63;
    int t  = (s >> 11) % 27;
    int ch = s / 55296;
    wT[s] = f2bf(w[(size_t)co*1728 + (size_t)(ch*32 + ci)*27 + t]);
}

// pack: channel-first f32 [b][64][R3] -> padded channel-last bf16 [b][2][RP3][32]
__global__ void k_pack(const float* __restrict__ src, ushort* __restrict__ gbf) {
    int s = blockIdx.x * 256 + threadIdx.x;      // grid 9826*256 = 2515456 exactly
    int j = s & 3;
    int tmp = s >> 2;
    int v = tmp % RP3;
    int t2 = tmp / RP3;
    int ch = t2 & 1, b = t2 >> 1;
    int gz = v / RP2; int r = v - gz*RP2;
    int gy = r / RP;  int gx = r - gy*RP;
    ushort8 o;
    if (gz >= 1 && gz <= 32 && gy >= 1 && gy <= 32 && gx >= 1 && gx <= 32) {
        int uvox = ((gz-1)*RR + (gy-1))*RR + (gx-1);
        #pragma unroll
        for (int e = 0; e < 8; e++)
            o[e] = f2bf(src[((size_t)(b*CC + ch*32 + j*8 + e))*R3 + uvox]);
    } else {
        #pragma unroll
        for (int e = 0; e < 8; e++) o[e] = 0;
    }
    *(ushort8*)(gbf + ((size_t)((b*2 + ch)*RP3) + v)*32 + j*8) = o;
}

// ---------------- MFMA conv (verified round-8) ----------------
__global__ __launch_bounds__(512) void k_conv_mfma(
    const ushort* __restrict__ gbf,   // [8][2][RP3][32] bf16
    const ushort* __restrict__ wT,    // [2][27][64][32] bf16
    float* __restrict__ outr)         // [8][64][R3] channel-first f32
{
    __shared__ uint4 lds4[3888];      // [3][18][18] rows x 4 chunks, 62208 B
    const int d0 = blockIdx.x, quad = blockIdx.y, b = blockIdx.z;
    const int y0 = (quad >> 1) * 16, x0 = (quad & 1) * 16;
    const int tid = threadIdx.x;
    const int lane = tid & 63;
    const int wid = tid >> 6;
    const int mgroup = wid & 1, ngroup = wid >> 1;
    const int l15 = lane & 15, kgrp = lane >> 4;

    f32x4 acc[2][4];
    #pragma unroll
    for (int mf = 0; mf < 2; mf++)
        #pragma unroll
        for (int f = 0; f < 4; f++) acc[mf][f] = (f32x4)(0.0f);

    for (int ch = 0; ch < 2; ch++) {
        __syncthreads();
        const char* gbase = (const char*)gbf + (size_t)(b*2 + ch) * ((size_t)RP3 * 64);
        for (int c = tid; c < 3888; c += 512) {
            int row = c >> 2, j = c & 3;
            int z = row / 324; int rem = row - z*324;
            int y = rem / 18;  int xl = rem - y*18;
            const uint4* gsrc = (const uint4*)(gbase +
                (size_t)((d0 + z)*RP2 + (y0 + y)*RP + (x0 + xl)) * 64);
            lds4[c] = gsrc[j];
        }
        __syncthreads();

        const ushort* wbase = wT + (size_t)ch * 27 * 2048;
        #pragma unroll
        for (int t0 = 0; t0 < 3; t0++)
        #pragma unroll
        for (int t1 = 0; t1 < 3; t1++)
        #pragma unroll
        for (int t2 = 0; t2 < 3; t2++) {
            int t = (t0*3 + t1)*3 + t2;
            short8 afr[2];
            #pragma unroll
            for (int mf = 0; mf < 2; mf++) {
                int co = mgroup*32 + mf*16 + l15;
                afr[mf] = *(const short8*)(wbase + (size_t)t*2048 + co*32 + kgrp*8);
            }
            int x = l15 + t2;
            #pragma unroll
            for (int f = 0; f < 4; f++) {
                int y = ngroup*4 + f + t1;
                int vox = (t0*18 + y)*18 + x;
                short8 bfr = *(const short8*)((const char*)lds4 + vox*64 + kgrp*16);
                acc[0][f] = __builtin_amdgcn_mfma_f32_16x16x32_bf16(afr[0], bfr, acc[0][f], 0, 0, 0);
                acc[1][f] = __builtin_amdgcn_mfma_f32_16x16x32_bf16(afr[1], bfr, acc[1][f], 0, 0, 0);
            }
        }
    }
    int d2 = x0 + l15;
    #pragma unroll
    for (int f = 0; f < 4; f++) {
        int d1 = y0 + ngroup*4 + f;
        int vox = (d0*RR + d1)*RR + d2;
        #pragma unroll
        for (int mf = 0; mf < 2; mf++) {
            #pragma unroll
            for (int e = 0; e < 4; e++) {
                int co = mgroup*32 + mf*16 + kgrp*4 + e;
                outr[((size_t)(b*CC + co))*R3 + vox] = acc[mf][f][e];
            }
        }
    }
}

// ---------------- BN pieces (verified round-8) ----------------
__global__ __launch_bounds__(256) void k_stats_cf(const float* __restrict__ x,
                                                  float* __restrict__ gs, float* __restrict__ gq) {
    __shared__ float ss[256], sq[256];
    int co = blockIdx.x, b = blockIdx.y;
    const float* p = x + ((size_t)(b*CC + co))*R3;
    float s = 0.f, q = 0.f;
    for (int i = threadIdx.x; i < R3; i += 256) { float v = p[i]; s += v; q += v*v; }
    int tid = threadIdx.x;
    ss[tid] = s; sq[tid] = q; __syncthreads();
    for (int off = 128; off > 0; off >>= 1) {
        if (tid < off) { ss[tid] += ss[tid + off]; sq[tid] += sq[tid + off]; }
        __syncthreads();
    }
    if (tid == 0) { atomicAdd(&gs[co], ss[0]); atomicAdd(&gq[co], sq[0]); }
}

__global__ void k_finalize(const float* __restrict__ ssum, const float* __restrict__ ssq,
                           const float* __restrict__ gamma, const float* __restrict__ beta,
                           float* __restrict__ scale, float* __restrict__ shift) {
    int c = threadIdx.x;
    const float cntf = 262144.0f;
    float m = ssum[c] / cntf;
    float v = ssq[c] / cntf - m*m;
    float sc = gamma[c] * rsqrtf(fmaxf(v, 0.0f) + BN_EPS);
    scale[c] = sc;
    shift[c] = beta[c] - m*sc;
}

__global__ void k_bnleaky(float* __restrict__ x, const float* __restrict__ scale,
                          const float* __restrict__ shift) {
    size_t tot = (size_t)BB * CC * R3;
    for (size_t i = (size_t)blockIdx.x*256 + threadIdx.x; i < tot; i += (size_t)gridDim.x*256) {
        int c = (int)((i >> 15) & 63);
        float v = x[i]*scale[c] + shift[c];
        x[i] = v >= 0.f ? v : 0.1f*v;
    }
}

// ---------------- point branch (verified round-8) ----------------
__global__ void k_point_stats(const float* __restrict__ feat, const float* __restrict__ wp,
                              const float* __restrict__ bp,
                              float* __restrict__ ssum, float* __restrict__ ssq) {
    __shared__ float sb1[256], sb2[256];
    int b = blockIdx.z, co = blockIdx.y;
    int n = blockIdx.x * 256 + threadIdx.x;
    float a = bp[co];
    const float* wr = wp + co*CC;
    #pragma unroll 8
    for (int ci = 0; ci < CC; ci++)
        a = fmaf(wr[ci], feat[((size_t)(b*CC + ci))*NPT + n], a);
    sb1[threadIdx.x] = a; sb2[threadIdx.x] = a*a; __syncthreads();
    for (int off = 128; off > 0; off >>= 1) {
        if (threadIdx.x < off) {
            sb1[threadIdx.x] += sb1[threadIdx.x + off];
            sb2[threadIdx.x] += sb2[threadIdx.x + off];
        }
        __syncthreads();
    }
    if (threadIdx.x == 0) { atomicAdd(&ssum[co], sb1[0]); atomicAdd(&ssq[co], sb2[0]); }
}

__global__ void k_final(const float* __restrict__ x2, const float* __restrict__ norm,
                        const float* __restrict__ feat, const float* __restrict__ wp,
                        const float* __restrict__ bp,
                        const float* __restrict__ scale, const float* __restrict__ shift,
                        float* __restrict__ out) {
    int b = blockIdx.z, co = blockIdx.y;
    int n = blockIdx.x * 256 + threadIdx.x;
    float a = bp[co];
    const float* wr = wp + co*CC;
    #pragma unroll 8
    for (int ci = 0; ci < CC; ci++)
        a = fmaf(wr[ci], feat[((size_t)(b*CC + ci))*NPT + n], a);
    a = a*scale[co] + shift[co];
    a = fmaxf(a, 0.f);
    float v0 = norm[((size_t)b*3 + 0)*NPT + n];
    float v1 = norm[((size_t)b*3 + 1)*NPT + n];
    float v2 = norm[((size_t)b*3 + 2)*NPT + n];
    int l0 = (int)floorf(v0), l1 = (int)floorf(v1), l2 = (int)floorf(v2);
    float f0 = v0 - (float)l0, f1 = v1 - (float)l1, f2 = v2 - (float)l2;
    int h0 = min(l0 + 1, RR - 1), h1 = min(l1 + 1, RR - 1), h2 = min(l2 + 1, RR - 1);
    const float* g = x2 + ((size_t)(b*CC + co))*R3;
    float acc = 0.f;
    #pragma unroll
    for (int dx = 0; dx < 2; dx++) {
        int xi = dx ? h0 : l0; float wx = dx ? f0 : 1.f - f0;
        #pragma unroll
        for (int dy = 0; dy < 2; dy++) {
            int yi = dy ? h1 : l1; float wy = dy ? f1 : 1.f - f1;
            #pragma unroll
            for (int dz = 0; dz < 2; dz++) {
                int zi = dz ? h2 : l2; float wz = dz ? f2 : 1.f - f2;
                acc += g[(xi*RR + yi)*RR + zi] * (wx*wy*wz);
            }
        }
    }
    out[((size_t)(b*CC + co))*NPT + n] = acc + a;
}

extern "C" void kernel_launch(void* const* d_in, const int* in_sizes, int n_in,
                              void* d_out, int out_size, void* d_ws, size_t ws_size,
                              hipStream_t stream) {
    const float* feat   = (const float*)d_in[0];
    const float* coords = (const float*)d_in[1];
    const float* w1  = (const float*)d_in[2];
    const float* g1  = (const float*)d_in[4];
    const float* be1 = (const float*)d_in[5];
    const float* w2  = (const float*)d_in[6];
    const float* g2  = (const float*)d_in[8];
    const float* be2 = (const float*)d_in[9];
    const float* wp  = (const float*)d_in[10];
    const float* bp  = (const float*)d_in[11];
    const float* gp  = (const float*)d_in[12];
    const float* bep = (const float*)d_in[13];
    float* out = (float*)d_out;
    float* ws  = (float*)d_ws;

    // workspace layout (float offsets) -- explicit end arithmetic:
    //   norm   786432   -> [1024, 787456)
    //   pidx   262144   -> [787456, 1049600)
    //   cnt    314432   -> [1049600, 1364032)     (8*RP3, padded)
    //   gridf  20123648 -> [1364032, 21487680)    padded CL f32 grid (overlays gA region)
    //   gA     16777216 -> [1364032, 18141248)    conv raw out; OVERLAPS gridf (gridf dead
    //                                             once k_divpack has produced gbf)
    //   wT1    55296    -> [21487680, 21542976)
    //   wT2    55296    -> [21542976, 21598272)
    //   gbf    10061824 -> [21598272, 31660096)
    //   featT  2097152  -> [31660096, 33757248)   = 135.03 MB total (proven ws >= 139.5 MB)
    float* mean   = ws;
    float* maxmag = ws + 24;
    float* stats  = ws + 32;
    float* sc     = ws + 416;
    float* norm   = ws + 1024;
    int*   pidx   = (int*)(ws + 787456);
    float* cnt    = ws + 1049600;
    float* gridf  = ws + 1364032;
    float* gA     = ws + 1364032;
    ushort* wT1   = (ushort*)(ws + 21487680);
    ushort* wT2   = (ushort*)(ws + 21542976);
    ushort* gbf   = (ushort*)(ws + 21598272);
    float* featT  = ws + 31660096;

    hipMemsetAsync(stats, 0, 384 * sizeof(float), stream);
    hipMemsetAsync(cnt,   0, 314432ull * sizeof(float), stream);
    hipMemsetAsync(gridf, 0, 20123648ull * sizeof(float), stream);

    k_wt<<<432, 256, 0, stream>>>(w1, wT1);
    k_wt<<<432, 256, 0, stream>>>(w2, wT2);

    k_mean  <<<24, 256, 0, stream>>>(coords, mean);
    k_maxmag<<<8, 256, 0, stream>>>(coords, mean, maxmag);
    k_norm  <<<dim3(128, 8), 256, 0, stream>>>(coords, mean, maxmag, norm, pidx, cnt);
    k_transpose<<<dim3(512, 8), 256, 0, stream>>>(feat, featT);
    k_scatter_cl<<<dim3(8192, 8), 256, 0, stream>>>(featT, pidx, gridf);
    k_divpack<<<9826, 256, 0, stream>>>(gridf, cnt, gbf);     // gridf dead after this

    // conv1: gbf -> gA (raw f32, overwrites gridf region)
    k_conv_mfma<<<dim3(32, 4, 8), 512, 0, stream>>>(gbf, wT1, gA);
    k_stats_cf<<<dim3(64, 8), 256, 0, stream>>>(gA, stats + 0, stats + 64);
    k_finalize<<<1, 64, 0, stream>>>(stats + 0, stats + 64, g1, be1, sc + 0, sc + 64);
    k_bnleaky<<<4096, 256, 0, stream>>>(gA, sc + 0, sc + 64);

    // conv2: gA -> gbf -> gA
    k_pack<<<9826, 256, 0, stream>>>(gA, gbf);
    k_conv_mfma<<<dim3(32, 4, 8), 512, 0, stream>>>(gbf, wT2, gA);
    k_stats_cf<<<dim3(64, 8), 256, 0, stream>>>(gA, stats + 128, stats + 192);
    k_finalize<<<1, 64, 0, stream>>>(stats + 128, stats + 192, g2, be2, sc + 128, sc + 192);
    k_bnleaky<<<4096, 256, 0, stream>>>(gA, sc + 128, sc + 192);

    // point branch + final
    k_point_stats<<<dim3(128, 64, 8), 256, 0, stream>>>(feat, wp, bp, stats + 256, stats + 320);
    k_finalize<<<1, 64, 0, stream>>>(stats + 256, stats + 320, gp, bep, sc + 256, sc + 320);
    k_final<<<dim3(128, 64, 8), 256, 0, stream>>>(gA, norm, feat, wp, bp, sc + 256, sc + 320, out);
}

// Round 10
// 805.102 us; speedup vs baseline: 7.6907x; 1.6708x over previous
//
#include <hip/hip_runtime.h>

typedef __attribute__((ext_vector_type(8))) short short8;
typedef __attribute__((ext_vector_type(8))) unsigned short ushort8;
typedef __attribute__((ext_vector_type(4))) float f32x4;
typedef unsigned int uint;
typedef unsigned short ushort;

#define BB 8
#define CC 64
#define NPT 32768
#define RR 32
#define R3 32768
#define RP 34
#define RP2 1156
#define RP3 39304
#define BN_EPS 1e-4f

__device__ __forceinline__ ushort f2bf(float x) {
    uint u = __float_as_uint(x);
    u = (u + 0x7FFFu + ((u >> 16) & 1u)) >> 16;
    return (ushort)u;
}

// ---------------- coord normalization ----------------
__global__ void k_mean(const float* __restrict__ coords, float* __restrict__ mean) {
    __shared__ float sbuf[256];
    int bd = blockIdx.x;
    const float* c = coords + (size_t)bd * NPT;
    float s = 0.f;
    for (int i = threadIdx.x; i < NPT; i += 256) s += c[i];
    sbuf[threadIdx.x] = s; __syncthreads();
    for (int off = 128; off > 0; off >>= 1) {
        if (threadIdx.x < off) sbuf[threadIdx.x] += sbuf[threadIdx.x + off];
        __syncthreads();
    }
    if (threadIdx.x == 0) mean[bd] = sbuf[0] / (float)NPT;
}

__global__ void k_maxmag(const float* __restrict__ coords, const float* __restrict__ mean,
                         float* __restrict__ maxmag) {
    __shared__ float sbuf[256];
    int b = blockIdx.x;
    float m0 = mean[b*3], m1 = mean[b*3+1], m2 = mean[b*3+2];
    const float* c = coords + (size_t)b * 3 * NPT;
    float mx = 0.f;
    for (int i = threadIdx.x; i < NPT; i += 256) {
        float x = c[i] - m0, y = c[NPT + i] - m1, z = c[2*NPT + i] - m2;
        mx = fmaxf(mx, x*x + y*y + z*z);
    }
    sbuf[threadIdx.x] = mx; __syncthreads();
    for (int off = 128; off > 0; off >>= 1) {
        if (threadIdx.x < off) sbuf[threadIdx.x] = fmaxf(sbuf[threadIdx.x], sbuf[threadIdx.x + off]);
        __syncthreads();
    }
    if (threadIdx.x == 0) maxmag[b] = sqrtf(sbuf[0]);
}

// writes PADDED flat voxel index pf (components in [1,32])
__global__ void k_norm(const float* __restrict__ coords, const float* __restrict__ mean,
                       const float* __restrict__ maxmag,
                       float* __restrict__ norm, int* __restrict__ pidx, float* __restrict__ cnt) {
    int b = blockIdx.y;
    int n = blockIdx.x * 256 + threadIdx.x;
    float denom = maxmag[b] * 2.0f;
    int vi[3];
    #pragma unroll
    for (int d = 0; d < 3; d++) {
        float v = (coords[((size_t)b*3 + d)*NPT + n] - mean[b*3 + d]) / denom + 0.5f;
        v *= (float)RR;
        v = fminf(fmaxf(v, 0.0f), (float)(RR - 1));
        norm[((size_t)b*3 + d)*NPT + n] = v;
        vi[d] = (int)rintf(v);
    }
    int pf = ((vi[0]+1)*RP + (vi[1]+1))*RP + (vi[2]+1);
    pidx[b*NPT + n] = pf;
    atomicAdd(&cnt[b*RP3 + pf], 1.0f);
}

// ---------------- feat transpose: [b][64][N] -> [b][N][64] ----------------
__global__ __launch_bounds__(256) void k_transpose(const float* __restrict__ feat,
                                                   float* __restrict__ featT) {
    __shared__ float t[64][65];
    int b = blockIdx.y;
    int n0 = blockIdx.x * 64;
    for (int i = threadIdx.x; i < 4096; i += 256) {
        int ci = i >> 6, nl = i & 63;
        t[ci][nl] = feat[((size_t)(b*CC + ci))*NPT + n0 + nl];
    }
    __syncthreads();
    for (int i = threadIdx.x; i < 4096; i += 256) {
        int nl = i >> 6, ci = i & 63;
        featT[((size_t)b*NPT + n0 + nl)*64 + ci] = t[ci][nl];
    }
}

// ---------------- channel-last scatter into padded f32 grid ----------------
__global__ void k_scatter_cl(const float* __restrict__ featT, const int* __restrict__ pidx,
                             float* __restrict__ gridf) {
    int b = blockIdx.y;
    int pt = blockIdx.x * 4 + (threadIdx.x >> 6);
    int ci = threadIdx.x & 63;
    atomicAdd(&gridf[((size_t)b*RP3 + pidx[b*NPT + pt])*64 + ci],
              featT[((size_t)b*NPT + pt)*64 + ci]);
}

// ---------------- fused divide-by-count + pack to bf16 [b][2][RP3][32] --------
__global__ void k_divpack(const float* __restrict__ gridf, const float* __restrict__ cnt,
                          ushort* __restrict__ gbf) {
    int s = blockIdx.x * 256 + threadIdx.x;      // grid 9826*256 = 2515456 exactly
    int j = s & 3;
    int tmp = s >> 2;
    int v = tmp % RP3;
    int t2 = tmp / RP3;
    int ch = t2 & 1, b = t2 >> 1;
    float rc = 1.0f / fmaxf(cnt[b*RP3 + v], 1.0f);
    const f32x4* src = (const f32x4*)(gridf + ((size_t)b*RP3 + v)*64 + ch*32 + j*8);
    f32x4 a = src[0], c4 = src[1];
    ushort8 o;
    #pragma unroll
    for (int e = 0; e < 4; e++) { o[e] = f2bf(a[e]*rc); o[4+e] = f2bf(c4[e]*rc); }
    *(ushort8*)(gbf + ((size_t)((b*2 + ch)*RP3) + v)*32 + j*8) = o;
}

// ---------------- weight transform (verified round-7) ----------------
__global__ void k_wt(const float* __restrict__ w, ushort* __restrict__ wT) {
    int s = blockIdx.x * 256 + threadIdx.x;     // grid 432*256 = 110592 exactly
    int ci = s & 31;
    int co = (s >> 5) & 63;
    int t  = (s >> 11) % 27;
    int ch = s / 55296;
    wT[s] = f2bf(w[(size_t)co*1728 + (size_t)(ch*32 + ci)*27 + t]);
}

// ---------------- fused BN+leaky+pack: CL raw f32 -> padded CL bf16 ----------
__global__ void k_bnpack(const float* __restrict__ raw, const float* __restrict__ sc,
                         const float* __restrict__ sh, ushort* __restrict__ gbf) {
    int s = blockIdx.x * 256 + threadIdx.x;      // grid 9826*256 = 2515456 exactly
    int j = s & 3;
    int tmp = s >> 2;
    int v = tmp % RP3;
    int t2 = tmp / RP3;
    int ch = t2 & 1, b = t2 >> 1;
    int gz = v / RP2; int r = v - gz*RP2;
    int gy = r / RP;  int gx = r - gy*RP;
    ushort8 o;
    if (gz >= 1 && gz <= 32 && gy >= 1 && gy <= 32 && gx >= 1 && gx <= 32) {
        int uvox = ((gz-1)*RR + (gy-1))*RR + (gx-1);
        int cb = ch*32 + j*8;
        const f32x4* src = (const f32x4*)(raw + ((size_t)b*R3 + uvox)*64 + cb);
        f32x4 a = src[0], c4 = src[1];
        f32x4 s0 = *(const f32x4*)(sc + cb), s1 = *(const f32x4*)(sc + cb + 4);
        f32x4 h0 = *(const f32x4*)(sh + cb), h1 = *(const f32x4*)(sh + cb + 4);
        #pragma unroll
        for (int e = 0; e < 4; e++) {
            float x0 = a[e]*s0[e] + h0[e];  x0 = x0 >= 0.f ? x0 : 0.1f*x0;
            float x1 = c4[e]*s1[e] + h1[e]; x1 = x1 >= 0.f ? x1 : 0.1f*x1;
            o[e] = f2bf(x0); o[4+e] = f2bf(x1);
        }
    } else {
        #pragma unroll
        for (int e = 0; e < 8; e++) o[e] = 0;
    }
    *(ushort8*)(gbf + ((size_t)((b*2 + ch)*RP3) + v)*32 + j*8) = o;
}

// ---------------- MFMA conv (verified round-8; epilogue now channel-last) ----
__global__ __launch_bounds__(512) void k_conv_mfma(
    const ushort* __restrict__ gbf,   // [8][2][RP3][32] bf16
    const ushort* __restrict__ wT,    // [2][27][64][32] bf16
    float* __restrict__ outr)         // [8][R3][64] channel-LAST f32
{
    __shared__ uint4 lds4[3888];      // [3][18][18] rows x 4 chunks, 62208 B
    const int d0 = blockIdx.x, quad = blockIdx.y, b = blockIdx.z;
    const int y0 = (quad >> 1) * 16, x0 = (quad & 1) * 16;
    const int tid = threadIdx.x;
    const int lane = tid & 63;
    const int wid = tid >> 6;
    const int mgroup = wid & 1, ngroup = wid >> 1;
    const int l15 = lane & 15, kgrp = lane >> 4;

    f32x4 acc[2][4];
    #pragma unroll
    for (int mf = 0; mf < 2; mf++)
        #pragma unroll
        for (int f = 0; f < 4; f++) acc[mf][f] = (f32x4)(0.0f);

    for (int ch = 0; ch < 2; ch++) {
        __syncthreads();
        const char* gbase = (const char*)gbf + (size_t)(b*2 + ch) * ((size_t)RP3 * 64);
        for (int c = tid; c < 3888; c += 512) {
            int row = c >> 2, j = c & 3;
            int z = row / 324; int rem = row - z*324;
            int y = rem / 18;  int xl = rem - y*18;
            const uint4* gsrc = (const uint4*)(gbase +
                (size_t)((d0 + z)*RP2 + (y0 + y)*RP + (x0 + xl)) * 64);
            lds4[c] = gsrc[j];
        }
        __syncthreads();

        const ushort* wbase = wT + (size_t)ch * 27 * 2048;
        #pragma unroll
        for (int t0 = 0; t0 < 3; t0++)
        #pragma unroll
        for (int t1 = 0; t1 < 3; t1++)
        #pragma unroll
        for (int t2 = 0; t2 < 3; t2++) {
            int t = (t0*3 + t1)*3 + t2;
            short8 afr[2];
            #pragma unroll
            for (int mf = 0; mf < 2; mf++) {
                int co = mgroup*32 + mf*16 + l15;
                afr[mf] = *(const short8*)(wbase + (size_t)t*2048 + co*32 + kgrp*8);
            }
            int x = l15 + t2;
            #pragma unroll
            for (int f = 0; f < 4; f++) {
                int y = ngroup*4 + f + t1;
                int vox = (t0*18 + y)*18 + x;
                short8 bfr = *(const short8*)((const char*)lds4 + vox*64 + kgrp*16);
                acc[0][f] = __builtin_amdgcn_mfma_f32_16x16x32_bf16(afr[0], bfr, acc[0][f], 0, 0, 0);
                acc[1][f] = __builtin_amdgcn_mfma_f32_16x16x32_bf16(afr[1], bfr, acc[1][f], 0, 0, 0);
            }
        }
    }
    // C/D: col = lane&15 (spatial x), row = kgrp*4 + e (co); channel-last vector store
    int d2 = x0 + l15;
    #pragma unroll
    for (int f = 0; f < 4; f++) {
        int d1 = y0 + ngroup*4 + f;
        int vox = (d0*RR + d1)*RR + d2;
        float* dst = outr + ((size_t)b*R3 + vox)*64 + mgroup*32 + kgrp*4;
        *(f32x4*)dst = acc[0][f];
        *(f32x4*)(dst + 16) = acc[1][f];
    }
}

// ---------------- channel-last BN stats (stride ≡ 0 mod 64) ----------------
__global__ __launch_bounds__(256) void k_stats_cl(const float* __restrict__ x,
                                                  float* __restrict__ gs, float* __restrict__ gq) {
    __shared__ float ss[256], sq[256];
    int gid = blockIdx.x * 256 + threadIdx.x;     // grid 1024 blocks
    float s = 0.f, q = 0.f;
    for (size_t i = gid; i < (size_t)BB*R3*64; i += 262144) {
        float v = x[i];
        s += v; q += v*v;
    }
    int tid = threadIdx.x;
    ss[tid] = s; sq[tid] = q; __syncthreads();
    if (tid < 128) { ss[tid] += ss[tid+128]; sq[tid] += sq[tid+128]; } __syncthreads();
    if (tid < 64)  { ss[tid] += ss[tid+64];  sq[tid] += sq[tid+64]; } __syncthreads();
    if (tid < 64) { atomicAdd(&gs[tid], ss[tid]); atomicAdd(&gq[tid], sq[tid]); }
}

__global__ void k_finalize(const float* __restrict__ ssum, const float* __restrict__ ssq,
                           const float* __restrict__ gamma, const float* __restrict__ beta,
                           float* __restrict__ scale, float* __restrict__ shift) {
    int c = threadIdx.x;
    const float cntf = 262144.0f;
    float m = ssum[c] / cntf;
    float v = ssq[c] / cntf - m*m;
    float sc = gamma[c] * rsqrtf(fmaxf(v, 0.0f) + BN_EPS);
    scale[c] = sc;
    shift[c] = beta[c] - m*sc;
}

// ---------------- BN+leaky in-place on channel-last conv2 raw ----------------
__global__ void k_bnleaky_cl(float* __restrict__ x, const float* __restrict__ sc,
                             const float* __restrict__ sh) {
    for (size_t i = (size_t)blockIdx.x*256 + threadIdx.x; i < (size_t)BB*R3*64;
         i += (size_t)gridDim.x*256) {
        int co = (int)(i & 63);
        float v = x[i]*sc[co] + sh[co];
        x[i] = v >= 0.f ? v : 0.1f*v;
    }
}

// ---------------- point branch stats: thread-owns-point ----------------
__global__ __launch_bounds__(256) void k_point_stats_cl(const float* __restrict__ featT,
                                                        const float* __restrict__ wp,
                                                        float* __restrict__ gs,
                                                        float* __restrict__ gq) {
    __shared__ float ls[64], lq[64];
    int b = blockIdx.y;
    int n = blockIdx.x * 256 + threadIdx.x;
    if (threadIdx.x < 64) { ls[threadIdx.x] = 0.f; lq[threadIdx.x] = 0.f; }
    __syncthreads();
    f32x4 fr[16];
    const f32x4* fp = (const f32x4*)(featT + ((size_t)b*NPT + n)*64);
    #pragma unroll
    for (int r = 0; r < 16; r++) fr[r] = fp[r];
    int lane = threadIdx.x & 63;
    #pragma unroll
    for (int co = 0; co < 64; co++) {
        float p = 0.f;
        #pragma unroll
        for (int r = 0; r < 16; r++) {
            f32x4 w4 = *(const f32x4*)(wp + co*64 + r*4);   // wave-uniform -> s_load
            p = fmaf(w4[0], fr[r][0], p); p = fmaf(w4[1], fr[r][1], p);
            p = fmaf(w4[2], fr[r][2], p); p = fmaf(w4[3], fr[r][3], p);
        }
        float s = p, q = p*p;
        #pragma unroll
        for (int m = 1; m < 64; m <<= 1) {
            s += __shfl_xor(s, m);
            q += __shfl_xor(q, m);
        }
        if (lane == 0) { atomicAdd(&ls[co], s); atomicAdd(&lq[co], q); }
    }
    __syncthreads();
    if (threadIdx.x < 64) {
        atomicAdd(&gs[threadIdx.x], ls[threadIdx.x]);
        atomicAdd(&gq[threadIdx.x], lq[threadIdx.x]);
    }
}

// ---------------- devoxelize + point branch + add: thread-owns-point ----------
__global__ __launch_bounds__(256) void k_final_cl(
    const float* __restrict__ x2,     // [B][R3][64] post-BN-leaky channel-last
    const float* __restrict__ norm,
    const float* __restrict__ featT,  // [B][N][64]
    const float* __restrict__ wp,
    const float* __restrict__ scp, const float* __restrict__ shp,
    float* __restrict__ out)          // [B][64][N]
{
    int b = blockIdx.y;
    int n = blockIdx.x * 256 + threadIdx.x;
    float v0 = norm[((size_t)b*3 + 0)*NPT + n];
    float v1 = norm[((size_t)b*3 + 1)*NPT + n];
    float v2 = norm[((size_t)b*3 + 2)*NPT + n];
    int l0 = (int)floorf(v0), l1 = (int)floorf(v1), l2 = (int)floorf(v2);
    float f0 = v0 - (float)l0, f1 = v1 - (float)l1, f2 = v2 - (float)l2;
    int h0 = min(l0 + 1, RR - 1), h1 = min(l1 + 1, RR - 1), h2 = min(l2 + 1, RR - 1);

    f32x4 a4[16];
    #pragma unroll
    for (int r = 0; r < 16; r++) a4[r] = (f32x4)(0.0f);
    #pragma unroll
    for (int c = 0; c < 8; c++) {
        int xi = (c & 4) ? h0 : l0; float wx = (c & 4) ? f0 : 1.f - f0;
        int yi = (c & 2) ? h1 : l1; float wy = (c & 2) ? f1 : 1.f - f1;
        int zi = (c & 1) ? h2 : l2; float wz = (c & 1) ? f2 : 1.f - f2;
        float w = wx * wy * wz;
        const f32x4* g = (const f32x4*)(x2 + ((size_t)b*R3 + (size_t)((xi*RR + yi)*RR + zi))*64);
        #pragma unroll
        for (int r = 0; r < 16; r++) a4[r] += w * g[r];
    }
    f32x4 fr[16];
    const f32x4* fp = (const f32x4*)(featT + ((size_t)b*NPT + n)*64);
    #pragma unroll
    for (int r = 0; r < 16; r++) fr[r] = fp[r];
    #pragma unroll
    for (int co = 0; co < 64; co++) {
        float p = 0.f;
        #pragma unroll
        for (int r = 0; r < 16; r++) {
            f32x4 w4 = *(const f32x4*)(wp + co*64 + r*4);   // wave-uniform -> s_load
            p = fmaf(w4[0], fr[r][0], p); p = fmaf(w4[1], fr[r][1], p);
            p = fmaf(w4[2], fr[r][2], p); p = fmaf(w4[3], fr[r][3], p);
        }
        p = p * scp[co] + shp[co];
        p = fmaxf(p, 0.f);
        out[((size_t)(b*64 + co))*NPT + n] = a4[co >> 2][co & 3] + p;
    }
}

extern "C" void kernel_launch(void* const* d_in, const int* in_sizes, int n_in,
                              void* d_out, int out_size, void* d_ws, size_t ws_size,
                              hipStream_t stream) {
    const float* feat   = (const float*)d_in[0];
    const float* coords = (const float*)d_in[1];
    const float* w1  = (const float*)d_in[2];
    const float* g1  = (const float*)d_in[4];
    const float* be1 = (const float*)d_in[5];
    const float* w2  = (const float*)d_in[6];
    const float* g2  = (const float*)d_in[8];
    const float* be2 = (const float*)d_in[9];
    const float* wp  = (const float*)d_in[10];
    const float* gp  = (const float*)d_in[12];
    const float* bep = (const float*)d_in[13];
    float* out = (float*)d_out;
    float* ws  = (float*)d_ws;

    // workspace layout (float offsets) -- explicit end arithmetic:
    //   norm   786432   -> [1024, 787456)
    //   pidx   262144   -> [787456, 1049600)
    //   cnt    314432   -> [1049600, 1364032)     (8*RP3)
    //   gridf  20123648 -> [1364032, 21487680)    padded CL f32 grid
    //   gA     16777216 -> [1364032, 18141248)    CL conv raw; overlays gridf (dead after divpack)
    //   wT1    55296    -> [21487680, 21542976)
    //   wT2    55296    -> [21542976, 21598272)
    //   gbf    10061824 -> [21598272, 31660096)
    //   featT  2097152  -> [31660096, 33757248)   = 135.03 MB total
    float* mean   = ws;
    float* maxmag = ws + 24;
    float* stats  = ws + 32;
    float* sc     = ws + 416;
    float* norm   = ws + 1024;
    int*   pidx   = (int*)(ws + 787456);
    float* cnt    = ws + 1049600;
    float* gridf  = ws + 1364032;
    float* gA     = ws + 1364032;
    ushort* wT1   = (ushort*)(ws + 21487680);
    ushort* wT2   = (ushort*)(ws + 21542976);
    ushort* gbf   = (ushort*)(ws + 21598272);
    float* featT  = ws + 31660096;

    hipMemsetAsync(stats, 0, 384 * sizeof(float), stream);
    hipMemsetAsync(cnt,   0, 314432ull * sizeof(float), stream);
    hipMemsetAsync(gridf, 0, 20123648ull * sizeof(float), stream);

    k_wt<<<432, 256, 0, stream>>>(w1, wT1);
    k_wt<<<432, 256, 0, stream>>>(w2, wT2);

    k_mean  <<<24, 256, 0, stream>>>(coords, mean);
    k_maxmag<<<8, 256, 0, stream>>>(coords, mean, maxmag);
    k_norm  <<<dim3(128, 8), 256, 0, stream>>>(coords, mean, maxmag, norm, pidx, cnt);
    k_transpose<<<dim3(512, 8), 256, 0, stream>>>(feat, featT);
    k_scatter_cl<<<dim3(8192, 8), 256, 0, stream>>>(featT, pidx, gridf);
    k_divpack<<<9826, 256, 0, stream>>>(gridf, cnt, gbf);     // gridf dead after this

    // conv1: gbf -> gA (CL raw f32, overwrites gridf region)
    k_conv_mfma<<<dim3(32, 4, 8), 512, 0, stream>>>(gbf, wT1, gA);
    k_stats_cl<<<1024, 256, 0, stream>>>(gA, stats + 0, stats + 64);
    k_finalize<<<1, 64, 0, stream>>>(stats + 0, stats + 64, g1, be1, sc + 0, sc + 64);
    // fused BN1+leaky+pack: gA -> gbf
    k_bnpack<<<9826, 256, 0, stream>>>(gA, sc + 0, sc + 64, gbf);

    // conv2: gbf -> gA (CL raw)
    k_conv_mfma<<<dim3(32, 4, 8), 512, 0, stream>>>(gbf, wT2, gA);
    k_stats_cl<<<1024, 256, 0, stream>>>(gA, stats + 128, stats + 192);
    k_finalize<<<1, 64, 0, stream>>>(stats + 128, stats + 192, g2, be2, sc + 128, sc + 192);
    k_bnleaky_cl<<<4096, 256, 0, stream>>>(gA, sc + 128, sc + 192);

    // point branch + final
    k_point_stats_cl<<<dim3(128, 8), 256, 0, stream>>>(featT, wp, stats + 256, stats + 320);
    k_finalize<<<1, 64, 0, stream>>>(stats + 256, stats + 320, gp, bep, sc + 256, sc + 320);
    k_final_cl<<<dim3(128, 8), 256, 0, stream>>>(gA, norm, featT, wp, sc + 256, sc + 320, out);
}

// Round 11
// 683.125 us; speedup vs baseline: 9.0639x; 1.1786x over previous
//
#include <hip/hip_runtime.h>

typedef __attribute__((ext_vector_type(8))) short short8;
typedef __attribute__((ext_vector_type(8))) unsigned short ushort8;
typedef __attribute__((ext_vector_type(4))) float f32x4;
typedef unsigned int uint;
typedef unsigned short ushort;

#define BB 8
#define CC 64
#define NPT 32768
#define RR 32
#define R3 32768
#define RP 34
#define RP2 1156
#define RP3 39304
#define BN_EPS 1e-4f

__device__ __forceinline__ ushort f2bf(float x) {
    uint u = __float_as_uint(x);
    u = (u + 0x7FFFu + ((u >> 16) & 1u)) >> 16;
    return (ushort)u;
}
__device__ __forceinline__ float bf2f(ushort u) {
    return __uint_as_float(((uint)u) << 16);
}

// ---------------- coord normalization ----------------
__global__ void k_mean(const float* __restrict__ coords, float* __restrict__ mean) {
    __shared__ float sbuf[256];
    int bd = blockIdx.x;
    const float* c = coords + (size_t)bd * NPT;
    float s = 0.f;
    for (int i = threadIdx.x; i < NPT; i += 256) s += c[i];
    sbuf[threadIdx.x] = s; __syncthreads();
    for (int off = 128; off > 0; off >>= 1) {
        if (threadIdx.x < off) sbuf[threadIdx.x] += sbuf[threadIdx.x + off];
        __syncthreads();
    }
    if (threadIdx.x == 0) mean[bd] = sbuf[0] / (float)NPT;
}

__global__ void k_maxmag(const float* __restrict__ coords, const float* __restrict__ mean,
                         float* __restrict__ maxmag) {
    __shared__ float sbuf[256];
    int b = blockIdx.x;
    float m0 = mean[b*3], m1 = mean[b*3+1], m2 = mean[b*3+2];
    const float* c = coords + (size_t)b * 3 * NPT;
    float mx = 0.f;
    for (int i = threadIdx.x; i < NPT; i += 256) {
        float x = c[i] - m0, y = c[NPT + i] - m1, z = c[2*NPT + i] - m2;
        mx = fmaxf(mx, x*x + y*y + z*z);
    }
    sbuf[threadIdx.x] = mx; __syncthreads();
    for (int off = 128; off > 0; off >>= 1) {
        if (threadIdx.x < off) sbuf[threadIdx.x] = fmaxf(sbuf[threadIdx.x], sbuf[threadIdx.x + off]);
        __syncthreads();
    }
    if (threadIdx.x == 0) maxmag[b] = sqrtf(sbuf[0]);
}

// writes PADDED flat voxel index pf (components in [1,32])
__global__ void k_norm(const float* __restrict__ coords, const float* __restrict__ mean,
                       const float* __restrict__ maxmag,
                       float* __restrict__ norm, int* __restrict__ pidx, float* __restrict__ cnt) {
    int b = blockIdx.y;
    int n = blockIdx.x * 256 + threadIdx.x;
    float denom = maxmag[b] * 2.0f;
    int vi[3];
    #pragma unroll
    for (int d = 0; d < 3; d++) {
        float v = (coords[((size_t)b*3 + d)*NPT + n] - mean[b*3 + d]) / denom + 0.5f;
        v *= (float)RR;
        v = fminf(fmaxf(v, 0.0f), (float)(RR - 1));
        norm[((size_t)b*3 + d)*NPT + n] = v;
        vi[d] = (int)rintf(v);
    }
    int pf = ((vi[0]+1)*RP + (vi[1]+1))*RP + (vi[2]+1);
    pidx[b*NPT + n] = pf;
    atomicAdd(&cnt[b*RP3 + pf], 1.0f);
}

// ---------------- feat transpose: [b][64][N] -> [b][N][64] ----------------
__global__ __launch_bounds__(256) void k_transpose(const float* __restrict__ feat,
                                                   float* __restrict__ featT) {
    __shared__ float t[64][65];
    int b = blockIdx.y;
    int n0 = blockIdx.x * 64;
    for (int i = threadIdx.x; i < 4096; i += 256) {
        int ci = i >> 6, nl = i & 63;
        t[ci][nl] = feat[((size_t)(b*CC + ci))*NPT + n0 + nl];
    }
    __syncthreads();
    for (int i = threadIdx.x; i < 4096; i += 256) {
        int nl = i >> 6, ci = i & 63;
        featT[((size_t)b*NPT + n0 + nl)*64 + ci] = t[ci][nl];
    }
}

// ---------------- channel-last scatter into padded f32 grid ----------------
__global__ void k_scatter_cl(const float* __restrict__ featT, const int* __restrict__ pidx,
                             float* __restrict__ gridf) {
    int b = blockIdx.y;
    int pt = blockIdx.x * 4 + (threadIdx.x >> 6);
    int ci = threadIdx.x & 63;
    atomicAdd(&gridf[((size_t)b*RP3 + pidx[b*NPT + pt])*64 + ci],
              featT[((size_t)b*NPT + pt)*64 + ci]);
}

// ---------------- fused divide-by-count + pack to bf16 [b][2][RP3][32] --------
__global__ void k_divpack(const float* __restrict__ gridf, const float* __restrict__ cnt,
                          ushort* __restrict__ gbf) {
    int s = blockIdx.x * 256 + threadIdx.x;      // grid 9826*256 = 2515456 exactly
    int j = s & 3;
    int tmp = s >> 2;
    int v = tmp % RP3;
    int t2 = tmp / RP3;
    int ch = t2 & 1, b = t2 >> 1;
    float rc = 1.0f / fmaxf(cnt[b*RP3 + v], 1.0f);
    const f32x4* src = (const f32x4*)(gridf + ((size_t)b*RP3 + v)*64 + ch*32 + j*8);
    f32x4 a = src[0], c4 = src[1];
    ushort8 o;
    #pragma unroll
    for (int e = 0; e < 4; e++) { o[e] = f2bf(a[e]*rc); o[4+e] = f2bf(c4[e]*rc); }
    *(ushort8*)(gbf + ((size_t)((b*2 + ch)*RP3) + v)*32 + j*8) = o;
}

// ---------------- weight transform (verified round-7) ----------------
__global__ void k_wt(const float* __restrict__ w, ushort* __restrict__ wT) {
    int s = blockIdx.x * 256 + threadIdx.x;     // grid 432*256 = 110592 exactly
    int ci = s & 31;
    int co = (s >> 5) & 63;
    int t  = (s >> 11) % 27;
    int ch = s / 55296;
    wT[s] = f2bf(w[(size_t)co*1728 + (size_t)(ch*32 + ci)*27 + t]);
}

// ---------------- fused BN+leaky+pack: CL raw f32 -> padded CL bf16 ----------
__global__ void k_bnpack(const float* __restrict__ raw, const float* __restrict__ sc,
                         const float* __restrict__ sh, ushort* __restrict__ gbf) {
    int s = blockIdx.x * 256 + threadIdx.x;      // grid 9826*256 = 2515456 exactly
    int j = s & 3;
    int tmp = s >> 2;
    int v = tmp % RP3;
    int t2 = tmp / RP3;
    int ch = t2 & 1, b = t2 >> 1;
    int gz = v / RP2; int r = v - gz*RP2;
    int gy = r / RP;  int gx = r - gy*RP;
    ushort8 o;
    if (gz >= 1 && gz <= 32 && gy >= 1 && gy <= 32 && gx >= 1 && gx <= 32) {
        int uvox = ((gz-1)*RR + (gy-1))*RR + (gx-1);
        int cb = ch*32 + j*8;
        const f32x4* src = (const f32x4*)(raw + ((size_t)b*R3 + uvox)*64 + cb);
        f32x4 a = src[0], c4 = src[1];
        f32x4 s0 = *(const f32x4*)(sc + cb), s1 = *(const f32x4*)(sc + cb + 4);
        f32x4 h0 = *(const f32x4*)(sh + cb), h1 = *(const f32x4*)(sh + cb + 4);
        #pragma unroll
        for (int e = 0; e < 4; e++) {
            float x0 = a[e]*s0[e] + h0[e];  x0 = x0 >= 0.f ? x0 : 0.1f*x0;
            float x1 = c4[e]*s1[e] + h1[e]; x1 = x1 >= 0.f ? x1 : 0.1f*x1;
            o[e] = f2bf(x0); o[4+e] = f2bf(x1);
        }
    } else {
        #pragma unroll
        for (int e = 0; e < 8; e++) o[e] = 0;
    }
    *(ushort8*)(gbf + ((size_t)((b*2 + ch)*RP3) + v)*32 + j*8) = o;
}

// ---------------- MFMA conv + inline BN stats ----------------
__global__ __launch_bounds__(512) void k_conv_mfma(
    const ushort* __restrict__ gbf,   // [8][2][RP3][32] bf16
    const ushort* __restrict__ wT,    // [2][27][64][32] bf16
    float* __restrict__ outr,         // [8][R3][64] channel-LAST f32
    float* __restrict__ gs, float* __restrict__ gq)
{
    __shared__ uint4 lds4[3888];      // [3][18][18] rows x 4 chunks, 62208 B
    const int d0 = blockIdx.x, quad = blockIdx.y, b = blockIdx.z;
    const int y0 = (quad >> 1) * 16, x0 = (quad & 1) * 16;
    const int tid = threadIdx.x;
    const int lane = tid & 63;
    const int wid = tid >> 6;
    const int mgroup = wid & 1, ngroup = wid >> 1;
    const int l15 = lane & 15, kgrp = lane >> 4;

    f32x4 acc[2][4];
    #pragma unroll
    for (int mf = 0; mf < 2; mf++)
        #pragma unroll
        for (int f = 0; f < 4; f++) acc[mf][f] = (f32x4)(0.0f);

    for (int ch = 0; ch < 2; ch++) {
        __syncthreads();
        const char* gbase = (const char*)gbf + (size_t)(b*2 + ch) * ((size_t)RP3 * 64);
        for (int c = tid; c < 3888; c += 512) {
            int row = c >> 2, j = c & 3;
            int z = row / 324; int rem = row - z*324;
            int y = rem / 18;  int xl = rem - y*18;
            const uint4* gsrc = (const uint4*)(gbase +
                (size_t)((d0 + z)*RP2 + (y0 + y)*RP + (x0 + xl)) * 64);
            lds4[c] = gsrc[j];
        }
        __syncthreads();

        const ushort* wbase = wT + (size_t)ch * 27 * 2048;
        #pragma unroll
        for (int t0 = 0; t0 < 3; t0++)
        #pragma unroll
        for (int t1 = 0; t1 < 3; t1++)
        #pragma unroll
        for (int t2 = 0; t2 < 3; t2++) {
            int t = (t0*3 + t1)*3 + t2;
            short8 afr[2];
            #pragma unroll
            for (int mf = 0; mf < 2; mf++) {
                int co = mgroup*32 + mf*16 + l15;
                afr[mf] = *(const short8*)(wbase + (size_t)t*2048 + co*32 + kgrp*8);
            }
            int x = l15 + t2;
            #pragma unroll
            for (int f = 0; f < 4; f++) {
                int y = ngroup*4 + f + t1;
                int vox = (t0*18 + y)*18 + x;
                short8 bfr = *(const short8*)((const char*)lds4 + vox*64 + kgrp*16);
                acc[0][f] = __builtin_amdgcn_mfma_f32_16x16x32_bf16(afr[0], bfr, acc[0][f], 0, 0, 0);
                acc[1][f] = __builtin_amdgcn_mfma_f32_16x16x32_bf16(afr[1], bfr, acc[1][f], 0, 0, 0);
            }
        }
    }
    // C/D: col = lane&15 (spatial x), row = kgrp*4 + e (co); channel-last vector store
    int d2 = x0 + l15;
    #pragma unroll
    for (int f = 0; f < 4; f++) {
        int d1 = y0 + ngroup*4 + f;
        int vox = (d0*RR + d1)*RR + d2;
        float* dst = outr + ((size_t)b*R3 + vox)*64 + mgroup*32 + kgrp*4;
        *(f32x4*)dst = acc[0][f];
        *(f32x4*)(dst + 16) = acc[1][f];
    }
    // ---- inline BN stats: per-thread f-sum, shuffle over l15, LDS bins, 1 atomic/co ----
    __syncthreads();                      // all MFMA reads of lds4 done
    float* bins = (float*)lds4;           // [0..63]=sum, [64..127]=sumsq
    if (tid < 128) bins[tid] = 0.f;
    __syncthreads();
    float sv[2][4], qv[2][4];
    #pragma unroll
    for (int mf = 0; mf < 2; mf++)
        #pragma unroll
        for (int e = 0; e < 4; e++) {
            float s = 0.f, q = 0.f;
            #pragma unroll
            for (int f = 0; f < 4; f++) {
                float v = acc[mf][f][e];
                s += v; q += v*v;
            }
            #pragma unroll
            for (int m = 1; m < 16; m <<= 1) {
                s += __shfl_xor(s, m);
                q += __shfl_xor(q, m);
            }
            sv[mf][e] = s; qv[mf][e] = q;
        }
    if (l15 == 0) {
        #pragma unroll
        for (int mf = 0; mf < 2; mf++)
            #pragma unroll
            for (int e = 0; e < 4; e++) {
                int co = mgroup*32 + mf*16 + kgrp*4 + e;
                atomicAdd(&bins[co], sv[mf][e]);
                atomicAdd(&bins[64 + co], qv[mf][e]);
            }
    }
    __syncthreads();
    if (tid < 64) { atomicAdd(&gs[tid], bins[tid]); atomicAdd(&gq[tid], bins[64 + tid]); }
}

__global__ void k_finalize(const float* __restrict__ ssum, const float* __restrict__ ssq,
                           const float* __restrict__ gamma, const float* __restrict__ beta,
                           float* __restrict__ scale, float* __restrict__ shift) {
    int c = threadIdx.x;
    const float cntf = 262144.0f;
    float m = ssum[c] / cntf;
    float v = ssq[c] / cntf - m*m;
    float sc = gamma[c] * rsqrtf(fmaxf(v, 0.0f) + BN_EPS);
    scale[c] = sc;
    shift[c] = beta[c] - m*sc;
}

// ---------------- point branch stats + store raw p as bf16 [b][64][N] --------
__global__ __launch_bounds__(256) void k_point_stats_P(const float* __restrict__ featT,
                                                       const float* __restrict__ wp,
                                                       ushort* __restrict__ P,
                                                       float* __restrict__ gs,
                                                       float* __restrict__ gq) {
    __shared__ float ls[64], lq[64];
    int b = blockIdx.y;
    int n = blockIdx.x * 256 + threadIdx.x;
    if (threadIdx.x < 64) { ls[threadIdx.x] = 0.f; lq[threadIdx.x] = 0.f; }
    __syncthreads();
    f32x4 fr[16];
    const f32x4* fp = (const f32x4*)(featT + ((size_t)b*NPT + n)*64);
    #pragma unroll
    for (int r = 0; r < 16; r++) fr[r] = fp[r];
    int lane = threadIdx.x & 63;
    #pragma unroll
    for (int co = 0; co < 64; co++) {
        float p = 0.f;
        #pragma unroll
        for (int r = 0; r < 16; r++) {
            f32x4 w4 = *(const f32x4*)(wp + co*64 + r*4);   // wave-uniform -> s_load
            p = fmaf(w4[0], fr[r][0], p); p = fmaf(w4[1], fr[r][1], p);
            p = fmaf(w4[2], fr[r][2], p); p = fmaf(w4[3], fr[r][3], p);
        }
        P[((size_t)(b*64 + co))*NPT + n] = f2bf(p);
        float s = p, q = p*p;
        #pragma unroll
        for (int m = 1; m < 64; m <<= 1) {
            s += __shfl_xor(s, m);
            q += __shfl_xor(q, m);
        }
        if (lane == 0) { atomicAdd(&ls[co], s); atomicAdd(&lq[co], q); }
    }
    __syncthreads();
    if (threadIdx.x < 64) {
        atomicAdd(&gs[threadIdx.x], ls[threadIdx.x]);
        atomicAdd(&gq[threadIdx.x], lq[threadIdx.x]);
    }
}

// ---------------- final: devox(bn2+leaky fused) + point-bn-relu + add --------
// 4 threads per point; thread owns a 16-channel quarter q = tid>>6 (wave-uniform).
__global__ __launch_bounds__(256) void k_final4(
    const float* __restrict__ x2raw,  // [B][R3][64] conv2 RAW channel-last
    const float* __restrict__ norm,
    const ushort* __restrict__ P,     // [B][64][N] bf16 point-branch raw
    const float* __restrict__ sc2, const float* __restrict__ sh2,
    const float* __restrict__ scp, const float* __restrict__ shp,
    float* __restrict__ out)          // [B][64][N]
{
    __shared__ float s_sc[64], s_sh[64];
    int b = blockIdx.y;
    int tid = threadIdx.x;
    if (tid < 64) { s_sc[tid] = sc2[tid]; s_sh[tid] = sh2[tid]; }
    __syncthreads();
    int pt = blockIdx.x * 64 + (tid & 63);
    int q = tid >> 6;                 // channel quarter, uniform per wave
    float v0 = norm[((size_t)b*3 + 0)*NPT + pt];
    float v1 = norm[((size_t)b*3 + 1)*NPT + pt];
    float v2 = norm[((size_t)b*3 + 2)*NPT + pt];
    int l0 = (int)floorf(v0), l1 = (int)floorf(v1), l2 = (int)floorf(v2);
    float f0 = v0 - (float)l0, f1 = v1 - (float)l1, f2 = v2 - (float)l2;
    int h0 = min(l0 + 1, RR - 1), h1 = min(l1 + 1, RR - 1), h2 = min(l2 + 1, RR - 1);

    f32x4 scv[4], shv[4];
    #pragma unroll
    for (int r = 0; r < 4; r++) {
        scv[r] = *(const f32x4*)&s_sc[q*16 + r*4];
        shv[r] = *(const f32x4*)&s_sh[q*16 + r*4];
    }

    f32x4 a4[4];
    #pragma unroll
    for (int r = 0; r < 4; r++) a4[r] = (f32x4)(0.0f);
    #pragma unroll
    for (int c = 0; c < 8; c++) {
        int xi = (c & 4) ? h0 : l0; float wx = (c & 4) ? f0 : 1.f - f0;
        int yi = (c & 2) ? h1 : l1; float wy = (c & 2) ? f1 : 1.f - f1;
        int zi = (c & 1) ? h2 : l2; float wz = (c & 1) ? f2 : 1.f - f2;
        float w = wx * wy * wz;
        const f32x4* g = (const f32x4*)(x2raw +
            ((size_t)b*R3 + (size_t)((xi*RR + yi)*RR + zi))*64 + q*16);
        #pragma unroll
        for (int r = 0; r < 4; r++) {
            f32x4 v = g[r];
            #pragma unroll
            for (int e = 0; e < 4; e++) {
                float x = v[e]*scv[r][e] + shv[r][e];       // BN2
                x = x >= 0.f ? x : 0.1f*x;                  // leaky
                a4[r][e] = fmaf(w, x, a4[r][e]);
            }
        }
    }
    #pragma unroll
    for (int r = 0; r < 4; r++) {
        #pragma unroll
        for (int e = 0; e < 4; e++) {
            int co = q*16 + r*4 + e;
            float p = bf2f(P[((size_t)(b*64 + co))*NPT + pt]);
            p = p * scp[co] + shp[co];
            p = fmaxf(p, 0.f);
            out[((size_t)(b*64 + co))*NPT + pt] = a4[r][e] + p;
        }
    }
}

extern "C" void kernel_launch(void* const* d_in, const int* in_sizes, int n_in,
                              void* d_out, int out_size, void* d_ws, size_t ws_size,
                              hipStream_t stream) {
    const float* feat   = (const float*)d_in[0];
    const float* coords = (const float*)d_in[1];
    const float* w1  = (const float*)d_in[2];
    const float* g1  = (const float*)d_in[4];
    const float* be1 = (const float*)d_in[5];
    const float* w2  = (const float*)d_in[6];
    const float* g2  = (const float*)d_in[8];
    const float* be2 = (const float*)d_in[9];
    const float* wp  = (const float*)d_in[10];
    const float* gp  = (const float*)d_in[12];
    const float* bep = (const float*)d_in[13];
    float* out = (float*)d_out;
    float* ws  = (float*)d_ws;

    // workspace layout (float offsets):
    //   norm   786432   -> [1024, 787456)
    //   pidx   262144   -> [787456, 1049600)
    //   cnt    314432   -> [1049600, 1364032)
    //   gridf  20123648 -> [1364032, 21487680)   padded CL f32 grid
    //   gA     16777216 -> [1364032, 18141248)   CL conv raw; overlays gridf (dead after divpack)
    //   wT1    55296    -> [21487680, 21542976)
    //   wT2    55296    -> [21542976, 21598272)
    //   gbf    10061824 -> [21598272, 31660096)
    //   P      8388608  -> [21598272, 29986880)  bf16 [8][64][N]; overlays gbf (dead after conv2)
    //   featT  2097152  -> [31660096, 33757248)  = 135.03 MB total
    float* mean   = ws;
    float* maxmag = ws + 24;
    float* stats  = ws + 32;
    float* sc     = ws + 416;
    float* norm   = ws + 1024;
    int*   pidx   = (int*)(ws + 787456);
    float* cnt    = ws + 1049600;
    float* gridf  = ws + 1364032;
    float* gA     = ws + 1364032;
    ushort* wT1   = (ushort*)(ws + 21487680);
    ushort* wT2   = (ushort*)(ws + 21542976);
    ushort* gbf   = (ushort*)(ws + 21598272);
    ushort* P     = (ushort*)(ws + 21598272);
    float* featT  = ws + 31660096;

    hipMemsetAsync(stats, 0, 384 * sizeof(float), stream);
    hipMemsetAsync(cnt,   0, 314432ull * sizeof(float), stream);
    hipMemsetAsync(gridf, 0, 20123648ull * sizeof(float), stream);

    k_wt<<<432, 256, 0, stream>>>(w1, wT1);
    k_wt<<<432, 256, 0, stream>>>(w2, wT2);

    k_mean  <<<24, 256, 0, stream>>>(coords, mean);
    k_maxmag<<<8, 256, 0, stream>>>(coords, mean, maxmag);
    k_norm  <<<dim3(128, 8), 256, 0, stream>>>(coords, mean, maxmag, norm, pidx, cnt);
    k_transpose<<<dim3(512, 8), 256, 0, stream>>>(feat, featT);
    k_scatter_cl<<<dim3(8192, 8), 256, 0, stream>>>(featT, pidx, gridf);
    k_divpack<<<9826, 256, 0, stream>>>(gridf, cnt, gbf);     // gridf dead after this

    // conv1 (+inline stats1): gbf -> gA
    k_conv_mfma<<<dim3(32, 4, 8), 512, 0, stream>>>(gbf, wT1, gA, stats + 0, stats + 64);
    k_finalize<<<1, 64, 0, stream>>>(stats + 0, stats + 64, g1, be1, sc + 0, sc + 64);
    // fused BN1+leaky+pack: gA -> gbf
    k_bnpack<<<9826, 256, 0, stream>>>(gA, sc + 0, sc + 64, gbf);

    // conv2 (+inline stats2): gbf -> gA; gbf dead afterwards
    k_conv_mfma<<<dim3(32, 4, 8), 512, 0, stream>>>(gbf, wT2, gA, stats + 128, stats + 192);
    k_finalize<<<1, 64, 0, stream>>>(stats + 128, stats + 192, g2, be2, sc + 128, sc + 192);

    // point branch: compute p once, store bf16 into P (overlays dead gbf), stats
    k_point_stats_P<<<dim3(128, 8), 256, 0, stream>>>(featT, wp, P, stats + 256, stats + 320);
    k_finalize<<<1, 64, 0, stream>>>(stats + 256, stats + 320, gp, bep, sc + 256, sc + 320);

    // final: devox with fused BN2+leaky on raw conv2 + point add
    k_final4<<<dim3(512, 8), 256, 0, stream>>>(gA, norm, P, sc + 128, sc + 192,
                                               sc + 256, sc + 320, out);
}

// Round 12
// 676.502 us; speedup vs baseline: 9.1526x; 1.0098x over previous
//
#include <hip/hip_runtime.h>

typedef __attribute__((ext_vector_type(8))) short short8;
typedef __attribute__((ext_vector_type(8))) unsigned short ushort8;
typedef __attribute__((ext_vector_type(4))) float f32x4;
typedef unsigned int uint;
typedef unsigned short ushort;

#define BB 8
#define CC 64
#define NPT 32768
#define RR 32
#define R3 32768
#define RP 34
#define RP2 1156
#define RP3 39304
#define BN_EPS 1e-4f

__device__ __forceinline__ ushort f2bf(float x) {
    uint u = __float_as_uint(x);
    u = (u + 0x7FFFu + ((u >> 16) & 1u)) >> 16;
    return (ushort)u;
}
__device__ __forceinline__ float bf2f(ushort u) {
    return __uint_as_float(((uint)u) << 16);
}
__device__ __forceinline__ void gload_lds16(const void* g, void* l) {
    __builtin_amdgcn_global_load_lds(
        (const __attribute__((address_space(1))) unsigned int*)g,
        (__attribute__((address_space(3))) unsigned int*)l, 16, 0, 0);
}

// ---------------- coord normalization ----------------
__global__ void k_mean(const float* __restrict__ coords, float* __restrict__ mean) {
    __shared__ float sbuf[256];
    int bd = blockIdx.x;
    const float* c = coords + (size_t)bd * NPT;
    float s = 0.f;
    for (int i = threadIdx.x; i < NPT; i += 256) s += c[i];
    sbuf[threadIdx.x] = s; __syncthreads();
    for (int off = 128; off > 0; off >>= 1) {
        if (threadIdx.x < off) sbuf[threadIdx.x] += sbuf[threadIdx.x + off];
        __syncthreads();
    }
    if (threadIdx.x == 0) mean[bd] = sbuf[0] / (float)NPT;
}

__global__ void k_maxmag(const float* __restrict__ coords, const float* __restrict__ mean,
                         float* __restrict__ maxmag) {
    __shared__ float sbuf[256];
    int b = blockIdx.x;
    float m0 = mean[b*3], m1 = mean[b*3+1], m2 = mean[b*3+2];
    const float* c = coords + (size_t)b * 3 * NPT;
    float mx = 0.f;
    for (int i = threadIdx.x; i < NPT; i += 256) {
        float x = c[i] - m0, y = c[NPT + i] - m1, z = c[2*NPT + i] - m2;
        mx = fmaxf(mx, x*x + y*y + z*z);
    }
    sbuf[threadIdx.x] = mx; __syncthreads();
    for (int off = 128; off > 0; off >>= 1) {
        if (threadIdx.x < off) sbuf[threadIdx.x] = fmaxf(sbuf[threadIdx.x], sbuf[threadIdx.x + off]);
        __syncthreads();
    }
    if (threadIdx.x == 0) maxmag[b] = sqrtf(sbuf[0]);
}

// writes PADDED flat voxel index pf (components in [1,32])
__global__ void k_norm(const float* __restrict__ coords, const float* __restrict__ mean,
                       const float* __restrict__ maxmag,
                       float* __restrict__ norm, int* __restrict__ pidx, float* __restrict__ cnt) {
    int b = blockIdx.y;
    int n = blockIdx.x * 256 + threadIdx.x;
    float denom = maxmag[b] * 2.0f;
    int vi[3];
    #pragma unroll
    for (int d = 0; d < 3; d++) {
        float v = (coords[((size_t)b*3 + d)*NPT + n] - mean[b*3 + d]) / denom + 0.5f;
        v *= (float)RR;
        v = fminf(fmaxf(v, 0.0f), (float)(RR - 1));
        norm[((size_t)b*3 + d)*NPT + n] = v;
        vi[d] = (int)rintf(v);
    }
    int pf = ((vi[0]+1)*RP + (vi[1]+1))*RP + (vi[2]+1);
    pidx[b*NPT + n] = pf;
    atomicAdd(&cnt[b*RP3 + pf], 1.0f);
}

// ---------------- feat transpose: [b][64][N] -> [b][N][64] ----------------
__global__ __launch_bounds__(256) void k_transpose(const float* __restrict__ feat,
                                                   float* __restrict__ featT) {
    __shared__ float t[64][65];
    int b = blockIdx.y;
    int n0 = blockIdx.x * 64;
    for (int i = threadIdx.x; i < 4096; i += 256) {
        int ci = i >> 6, nl = i & 63;
        t[ci][nl] = feat[((size_t)(b*CC + ci))*NPT + n0 + nl];
    }
    __syncthreads();
    for (int i = threadIdx.x; i < 4096; i += 256) {
        int nl = i >> 6, ci = i & 63;
        featT[((size_t)b*NPT + n0 + nl)*64 + ci] = t[ci][nl];
    }
}

// ---------------- channel-last scatter into padded f32 grid ----------------
__global__ void k_scatter_cl(const float* __restrict__ featT, const int* __restrict__ pidx,
                             float* __restrict__ gridf) {
    int b = blockIdx.y;
    int pt = blockIdx.x * 4 + (threadIdx.x >> 6);
    int ci = threadIdx.x & 63;
    atomicAdd(&gridf[((size_t)b*RP3 + pidx[b*NPT + pt])*64 + ci],
              featT[((size_t)b*NPT + pt)*64 + ci]);
}

// ---------------- fused divide-by-count + pack to bf16 [b][2][RP3][32] --------
__global__ void k_divpack(const float* __restrict__ gridf, const float* __restrict__ cnt,
                          ushort* __restrict__ gbf) {
    int s = blockIdx.x * 256 + threadIdx.x;      // grid 9826*256 = 2515456 exactly
    int j = s & 3;
    int tmp = s >> 2;
    int v = tmp % RP3;
    int t2 = tmp / RP3;
    int ch = t2 & 1, b = t2 >> 1;
    float rc = 1.0f / fmaxf(cnt[b*RP3 + v], 1.0f);
    const f32x4* src = (const f32x4*)(gridf + ((size_t)b*RP3 + v)*64 + ch*32 + j*8);
    f32x4 a = src[0], c4 = src[1];
    ushort8 o;
    #pragma unroll
    for (int e = 0; e < 4; e++) { o[e] = f2bf(a[e]*rc); o[4+e] = f2bf(c4[e]*rc); }
    *(ushort8*)(gbf + ((size_t)((b*2 + ch)*RP3) + v)*32 + j*8) = o;
}

// ---------------- weight transform (verified round-7) ----------------
__global__ void k_wt(const float* __restrict__ w, ushort* __restrict__ wT) {
    int s = blockIdx.x * 256 + threadIdx.x;     // grid 432*256 = 110592 exactly
    int ci = s & 31;
    int co = (s >> 5) & 63;
    int t  = (s >> 11) % 27;
    int ch = s / 55296;
    wT[s] = f2bf(w[(size_t)co*1728 + (size_t)(ch*32 + ci)*27 + t]);
}

// ---------------- fused BN+leaky+pack: CL raw f32 -> padded CL bf16 ----------
__global__ void k_bnpack(const float* __restrict__ raw, const float* __restrict__ sc,
                         const float* __restrict__ sh, ushort* __restrict__ gbf) {
    int s = blockIdx.x * 256 + threadIdx.x;      // grid 9826*256 = 2515456 exactly
    int j = s & 3;
    int tmp = s >> 2;
    int v = tmp % RP3;
    int t2 = tmp / RP3;
    int ch = t2 & 1, b = t2 >> 1;
    int gz = v / RP2; int r = v - gz*RP2;
    int gy = r / RP;  int gx = r - gy*RP;
    ushort8 o;
    if (gz >= 1 && gz <= 32 && gy >= 1 && gy <= 32 && gx >= 1 && gx <= 32) {
        int uvox = ((gz-1)*RR + (gy-1))*RR + (gx-1);
        int cb = ch*32 + j*8;
        const f32x4* src = (const f32x4*)(raw + ((size_t)b*R3 + uvox)*64 + cb);
        f32x4 a = src[0], c4 = src[1];
        f32x4 s0 = *(const f32x4*)(sc + cb), s1 = *(const f32x4*)(sc + cb + 4);
        f32x4 h0 = *(const f32x4*)(sh + cb), h1 = *(const f32x4*)(sh + cb + 4);
        #pragma unroll
        for (int e = 0; e < 4; e++) {
            float x0 = a[e]*s0[e] + h0[e];  x0 = x0 >= 0.f ? x0 : 0.1f*x0;
            float x1 = c4[e]*s1[e] + h1[e]; x1 = x1 >= 0.f ? x1 : 0.1f*x1;
            o[e] = f2bf(x0); o[4+e] = f2bf(x1);
        }
    } else {
        #pragma unroll
        for (int e = 0; e < 8; e++) o[e] = 0;
    }
    *(ushort8*)(gbf + ((size_t)((b*2 + ch)*RP3) + v)*32 + j*8) = o;
}

// ---------------- MFMA conv + inline BN stats ----------------
// LDS: [3][18][18] rows of 64B. 16B slot j of row with local-x holds GLOBAL chunk
// j ^ ((x>>1)&3)  (pre-swizzled source, linear global_load_lds dest).
// Read inverts: chunk kgrp lives at slot kgrp ^ ((x>>1)&3).
__global__ __launch_bounds__(512) void k_conv_mfma(
    const ushort* __restrict__ gbf,   // [8][2][RP3][32] bf16
    const ushort* __restrict__ wT,    // [2][27][64][32] bf16
    float* __restrict__ outr,         // [8][R3][64] channel-LAST f32
    float* __restrict__ gs, float* __restrict__ gq)
{
    __shared__ uint4 lds4[3888];      // 62208 B
    const int d0 = blockIdx.x, quad = blockIdx.y, b = blockIdx.z;
    const int y0 = (quad >> 1) * 16, x0 = (quad & 1) * 16;
    const int tid = threadIdx.x;
    const int lane = tid & 63;
    const int wid = tid >> 6;
    const int mgroup = wid & 1, ngroup = wid >> 1;
    const int l15 = lane & 15, kgrp = lane >> 4;

    f32x4 acc[2][4];
    #pragma unroll
    for (int mf = 0; mf < 2; mf++)
        #pragma unroll
        for (int f = 0; f < 4; f++) acc[mf][f] = (f32x4)(0.0f);

    for (int ch = 0; ch < 2; ch++) {
        __syncthreads();
        const char* gbase = (const char*)gbf + (size_t)(b*2 + ch) * ((size_t)RP3 * 64);
        for (int c = tid; c < 3888; c += 512) {
            int row = c >> 2, j = c & 3;
            int z = row / 324; int rem = row - z*324;
            int y = rem / 18;  int xl = rem - y*18;
            int srcj = j ^ ((xl >> 1) & 3);     // pre-swizzled source chunk
            const char* src = gbase +
                (size_t)((d0 + z)*RP2 + (y0 + y)*RP + (x0 + xl)) * 64 + srcj*16;
            gload_lds16(src, (char*)lds4 + c*16);   // linear LDS dest
        }
        __syncthreads();

        const ushort* wbase = wT + (size_t)ch * 27 * 2048;
        #pragma unroll
        for (int t0 = 0; t0 < 3; t0++)
        #pragma unroll
        for (int t1 = 0; t1 < 3; t1++)
        #pragma unroll
        for (int t2 = 0; t2 < 3; t2++) {
            int t = (t0*3 + t1)*3 + t2;
            short8 afr[2];
            #pragma unroll
            for (int mf = 0; mf < 2; mf++) {
                int co = mgroup*32 + mf*16 + l15;
                afr[mf] = *(const short8*)(wbase + (size_t)t*2048 + co*32 + kgrp*8);
            }
            int x = l15 + t2;
            int inrow = (kgrp ^ ((x >> 1) & 3)) << 4;   // swizzled read slot
            #pragma unroll
            for (int f = 0; f < 4; f++) {
                int y = ngroup*4 + f + t1;
                int vox = (t0*18 + y)*18 + x;
                short8 bfr = *(const short8*)((const char*)lds4 + vox*64 + inrow);
                acc[0][f] = __builtin_amdgcn_mfma_f32_16x16x32_bf16(afr[0], bfr, acc[0][f], 0, 0, 0);
                acc[1][f] = __builtin_amdgcn_mfma_f32_16x16x32_bf16(afr[1], bfr, acc[1][f], 0, 0, 0);
            }
        }
    }
    // C/D: col = lane&15 (spatial x), row = kgrp*4 + e (co); channel-last vector store
    int d2 = x0 + l15;
    #pragma unroll
    for (int f = 0; f < 4; f++) {
        int d1 = y0 + ngroup*4 + f;
        int vox = (d0*RR + d1)*RR + d2;
        float* dst = outr + ((size_t)b*R3 + vox)*64 + mgroup*32 + kgrp*4;
        *(f32x4*)dst = acc[0][f];
        *(f32x4*)(dst + 16) = acc[1][f];
    }
    // ---- inline BN stats ----
    __syncthreads();
    float* bins = (float*)lds4;
    if (tid < 128) bins[tid] = 0.f;
    __syncthreads();
    float sv[2][4], qv[2][4];
    #pragma unroll
    for (int mf = 0; mf < 2; mf++)
        #pragma unroll
        for (int e = 0; e < 4; e++) {
            float s = 0.f, q = 0.f;
            #pragma unroll
            for (int f = 0; f < 4; f++) {
                float v = acc[mf][f][e];
                s += v; q += v*v;
            }
            #pragma unroll
            for (int m = 1; m < 16; m <<= 1) {
                s += __shfl_xor(s, m);
                q += __shfl_xor(q, m);
            }
            sv[mf][e] = s; qv[mf][e] = q;
        }
    if (l15 == 0) {
        #pragma unroll
        for (int mf = 0; mf < 2; mf++)
            #pragma unroll
            for (int e = 0; e < 4; e++) {
                int co = mgroup*32 + mf*16 + kgrp*4 + e;
                atomicAdd(&bins[co], sv[mf][e]);
                atomicAdd(&bins[64 + co], qv[mf][e]);
            }
    }
    __syncthreads();
    if (tid < 64) { atomicAdd(&gs[tid], bins[tid]); atomicAdd(&gq[tid], bins[64 + tid]); }
}

__global__ void k_finalize(const float* __restrict__ ssum, const float* __restrict__ ssq,
                           const float* __restrict__ gamma, const float* __restrict__ beta,
                           float* __restrict__ scale, float* __restrict__ shift) {
    int c = threadIdx.x;
    const float cntf = 262144.0f;
    float m = ssum[c] / cntf;
    float v = ssq[c] / cntf - m*m;
    float sc = gamma[c] * rsqrtf(fmaxf(v, 0.0f) + BN_EPS);
    scale[c] = sc;
    shift[c] = beta[c] - m*sc;
}

// ---------------- point branch stats + store raw p as bf16 [b][64][N] --------
__global__ __launch_bounds__(256) void k_point_stats_P(const float* __restrict__ featT,
                                                       const float* __restrict__ wp,
                                                       ushort* __restrict__ P,
                                                       float* __restrict__ gs,
                                                       float* __restrict__ gq) {
    __shared__ float ls[64], lq[64];
    int b = blockIdx.y;
    int n = blockIdx.x * 256 + threadIdx.x;
    if (threadIdx.x < 64) { ls[threadIdx.x] = 0.f; lq[threadIdx.x] = 0.f; }
    __syncthreads();
    f32x4 fr[16];
    const f32x4* fp = (const f32x4*)(featT + ((size_t)b*NPT + n)*64);
    #pragma unroll
    for (int r = 0; r < 16; r++) fr[r] = fp[r];
    int lane = threadIdx.x & 63;
    #pragma unroll
    for (int co = 0; co < 64; co++) {
        float p = 0.f;
        #pragma unroll
        for (int r = 0; r < 16; r++) {
            f32x4 w4 = *(const f32x4*)(wp + co*64 + r*4);   // wave-uniform -> s_load
            p = fmaf(w4[0], fr[r][0], p); p = fmaf(w4[1], fr[r][1], p);
            p = fmaf(w4[2], fr[r][2], p); p = fmaf(w4[3], fr[r][3], p);
        }
        P[((size_t)(b*64 + co))*NPT + n] = f2bf(p);
        float s = p, q = p*p;
        #pragma unroll
        for (int m = 1; m < 64; m <<= 1) {
            s += __shfl_xor(s, m);
            q += __shfl_xor(q, m);
        }
        if (lane == 0) { atomicAdd(&ls[co], s); atomicAdd(&lq[co], q); }
    }
    __syncthreads();
    if (threadIdx.x < 64) {
        atomicAdd(&gs[threadIdx.x], ls[threadIdx.x]);
        atomicAdd(&gq[threadIdx.x], lq[threadIdx.x]);
    }
}

// ---------------- final: devox(bn2+leaky fused) + point-bn-relu + add --------
__global__ __launch_bounds__(256) void k_final4(
    const float* __restrict__ x2raw,  // [B][R3][64] conv2 RAW channel-last
    const float* __restrict__ norm,
    const ushort* __restrict__ P,     // [B][64][N] bf16 point-branch raw
    const float* __restrict__ sc2, const float* __restrict__ sh2,
    const float* __restrict__ scp, const float* __restrict__ shp,
    float* __restrict__ out)          // [B][64][N]
{
    __shared__ float s_sc[64], s_sh[64];
    int b = blockIdx.y;
    int tid = threadIdx.x;
    if (tid < 64) { s_sc[tid] = sc2[tid]; s_sh[tid] = sh2[tid]; }
    __syncthreads();
    int pt = blockIdx.x * 64 + (tid & 63);
    int q = tid >> 6;                 // channel quarter, uniform per wave
    float v0 = norm[((size_t)b*3 + 0)*NPT + pt];
    float v1 = norm[((size_t)b*3 + 1)*NPT + pt];
    float v2 = norm[((size_t)b*3 + 2)*NPT + pt];
    int l0 = (int)floorf(v0), l1 = (int)floorf(v1), l2 = (int)floorf(v2);
    float f0 = v0 - (float)l0, f1 = v1 - (float)l1, f2 = v2 - (float)l2;
    int h0 = min(l0 + 1, RR - 1), h1 = min(l1 + 1, RR - 1), h2 = min(l2 + 1, RR - 1);

    f32x4 scv[4], shv[4];
    #pragma unroll
    for (int r = 0; r < 4; r++) {
        scv[r] = *(const f32x4*)&s_sc[q*16 + r*4];
        shv[r] = *(const f32x4*)&s_sh[q*16 + r*4];
    }

    f32x4 a4[4];
    #pragma unroll
    for (int r = 0; r < 4; r++) a4[r] = (f32x4)(0.0f);
    #pragma unroll
    for (int c = 0; c < 8; c++) {
        int xi = (c & 4) ? h0 : l0; float wx = (c & 4) ? f0 : 1.f - f0;
        int yi = (c & 2) ? h1 : l1; float wy = (c & 2) ? f1 : 1.f - f1;
        int zi = (c & 1) ? h2 : l2; float wz = (c & 1) ? f2 : 1.f - f2;
        float w = wx * wy * wz;
        const f32x4* g = (const f32x4*)(x2raw +
            ((size_t)b*R3 + (size_t)((xi*RR + yi)*RR + zi))*64 + q*16);
        #pragma unroll
        for (int r = 0; r < 4; r++) {
            f32x4 v = g[r];
            #pragma unroll
            for (int e = 0; e < 4; e++) {
                float x = v[e]*scv[r][e] + shv[r][e];       // BN2
                x = x >= 0.f ? x : 0.1f*x;                  // leaky
                a4[r][e] = fmaf(w, x, a4[r][e]);
            }
        }
    }
    #pragma unroll
    for (int r = 0; r < 4; r++) {
        #pragma unroll
        for (int e = 0; e < 4; e++) {
            int co = q*16 + r*4 + e;
            float p = bf2f(P[((size_t)(b*64 + co))*NPT + pt]);
            p = p * scp[co] + shp[co];
            p = fmaxf(p, 0.f);
            out[((size_t)(b*64 + co))*NPT + pt] = a4[r][e] + p;
        }
    }
}

extern "C" void kernel_launch(void* const* d_in, const int* in_sizes, int n_in,
                              void* d_out, int out_size, void* d_ws, size_t ws_size,
                              hipStream_t stream) {
    const float* feat   = (const float*)d_in[0];
    const float* coords = (const float*)d_in[1];
    const float* w1  = (const float*)d_in[2];
    const float* g1  = (const float*)d_in[4];
    const float* be1 = (const float*)d_in[5];
    const float* w2  = (const float*)d_in[6];
    const float* g2  = (const float*)d_in[8];
    const float* be2 = (const float*)d_in[9];
    const float* wp  = (const float*)d_in[10];
    const float* gp  = (const float*)d_in[12];
    const float* bep = (const float*)d_in[13];
    float* out = (float*)d_out;
    float* ws  = (float*)d_ws;

    // workspace layout (float offsets):
    //   norm   786432   -> [1024, 787456)
    //   pidx   262144   -> [787456, 1049600)
    //   cnt    314432   -> [1049600, 1364032)
    //   gridf  20123648 -> [1364032, 21487680)   padded CL f32 grid
    //   gA     16777216 -> [1364032, 18141248)   CL conv raw; overlays gridf (dead after divpack)
    //   wT1    55296    -> [21487680, 21542976)
    //   wT2    55296    -> [21542976, 21598272)
    //   gbf    10061824 -> [21598272, 31660096)
    //   P      8388608  -> [21598272, 29986880)  bf16 [8][64][N]; overlays gbf (dead after conv2)
    //   featT  2097152  -> [31660096, 33757248)  = 135.03 MB total
    float* mean   = ws;
    float* maxmag = ws + 24;
    float* stats  = ws + 32;
    float* sc     = ws + 416;
    float* norm   = ws + 1024;
    int*   pidx   = (int*)(ws + 787456);
    float* cnt    = ws + 1049600;
    float* gridf  = ws + 1364032;
    float* gA     = ws + 1364032;
    ushort* wT1   = (ushort*)(ws + 21487680);
    ushort* wT2   = (ushort*)(ws + 21542976);
    ushort* gbf   = (ushort*)(ws + 21598272);
    ushort* P     = (ushort*)(ws + 21598272);
    float* featT  = ws + 31660096;

    hipMemsetAsync(stats, 0, 384 * sizeof(float), stream);
    hipMemsetAsync(cnt,   0, 314432ull * sizeof(float), stream);
    hipMemsetAsync(gridf, 0, 20123648ull * sizeof(float), stream);

    k_wt<<<432, 256, 0, stream>>>(w1, wT1);
    k_wt<<<432, 256, 0, stream>>>(w2, wT2);

    k_mean  <<<24, 256, 0, stream>>>(coords, mean);
    k_maxmag<<<8, 256, 0, stream>>>(coords, mean, maxmag);
    k_norm  <<<dim3(128, 8), 256, 0, stream>>>(coords, mean, maxmag, norm, pidx, cnt);
    k_transpose<<<dim3(512, 8), 256, 0, stream>>>(feat, featT);
    k_scatter_cl<<<dim3(8192, 8), 256, 0, stream>>>(featT, pidx, gridf);
    k_divpack<<<9826, 256, 0, stream>>>(gridf, cnt, gbf);     // gridf dead after this

    // conv1 (+inline stats1): gbf -> gA
    k_conv_mfma<<<dim3(32, 4, 8), 512, 0, stream>>>(gbf, wT1, gA, stats + 0, stats + 64);
    k_finalize<<<1, 64, 0, stream>>>(stats + 0, stats + 64, g1, be1, sc + 0, sc + 64);
    // fused BN1+leaky+pack: gA -> gbf
    k_bnpack<<<9826, 256, 0, stream>>>(gA, sc + 0, sc + 64, gbf);

    // conv2 (+inline stats2): gbf -> gA; gbf dead afterwards
    k_conv_mfma<<<dim3(32, 4, 8), 512, 0, stream>>>(gbf, wT2, gA, stats + 128, stats + 192);
    k_finalize<<<1, 64, 0, stream>>>(stats + 128, stats + 192, g2, be2, sc + 128, sc + 192);

    // point branch: compute p once, store bf16 into P (overlays dead gbf), stats
    k_point_stats_P<<<dim3(128, 8), 256, 0, stream>>>(featT, wp, P, stats + 256, stats + 320);
    k_finalize<<<1, 64, 0, stream>>>(stats + 256, stats + 320, gp, bep, sc + 256, sc + 320);

    // final: devox with fused BN2+leaky on raw conv2 + point add
    k_final4<<<dim3(512, 8), 256, 0, stream>>>(gA, norm, P, sc + 128, sc + 192,
                                               sc + 256, sc + 320, out);
}